// Round 1
// baseline (1478.183 us; speedup 1.0000x reference)
//
#include <hip/hip_runtime.h>
#include <math.h>

// Problem constants
#define NTOK 4096
#define PCH  128
#define ICH  256
#define OCH  128
#define NB   2
#define SCALEF 0.08838834764831845f   // 1/sqrt(128) in f32

// ---------------------------------------------------------------------------
// K0: fc2 — ri[b][p][n] = sum_c img[b][c][n] * w[p][c] + bias[p]
// block = 256 threads = 64 n  x  4 p-groups (32 p each). w reads are
// wave-uniform -> scalar loads. img reads coalesced along n.
// ---------------------------------------------------------------------------
__global__ __launch_bounds__(256) void fc2_kernel(const float* __restrict__ img,
                                                  const float* __restrict__ w,
                                                  const float* __restrict__ bias,
                                                  float* __restrict__ ri)
{
    const int b  = blockIdx.y;
    const int t  = threadIdx.x;
    const int n  = blockIdx.x * 64 + (t & 63);
    const int pg = t >> 6;                       // wave-uniform (0..3)
    const float* imgb = img + b * ICH * NTOK;
    float* rib = ri + b * PCH * NTOK;

    float acc[32];
#pragma unroll
    for (int pp = 0; pp < 32; pp++) acc[pp] = bias[pg * 32 + pp];
    for (int c = 0; c < ICH; c++) {
        const float v = imgb[c * NTOK + n];
#pragma unroll
        for (int pp = 0; pp < 32; pp++)
            acc[pp] += w[(pg * 32 + pp) * ICH + c] * v;
    }
#pragma unroll
    for (int pp = 0; pp < 32; pp++)
        rib[(pg * 32 + pp) * NTOK + n] = acc[pp];
}

// ---------------------------------------------------------------------------
// K1: stats — zout[i] = sum_j exp(scale * A_i . B_j)
// mode 0: A=rp, B=ri -> row sums z_i.  mode 1: A=ri, B=rp -> col sums Z_m.
// Row band of 64 i per block; j in tiles of 64; no max-subtraction needed
// (|S| < ~7 for these unit-normal inputs). No atomics, no memset.
// A band staged in LDS (k-major); B fragments stream from global (L2-hot).
// ---------------------------------------------------------------------------
__global__ __launch_bounds__(256) void stats_kernel(const float* __restrict__ pf,
                                                    const float* __restrict__ ri,
                                                    float* __restrict__ zrow,
                                                    float* __restrict__ zcol)
{
    __shared__ float As[128][64];   // 32 KB, [k][i]

    const int b    = blockIdx.y;
    const int mode = blockIdx.z;
    const float* A  = (mode == 0 ? pf : ri) + b * PCH * NTOK;
    const float* Bm = (mode == 0 ? ri : pf) + b * PCH * NTOK;
    float* zout = (mode == 0 ? zrow : zcol) + b * NTOK;

    const int t  = threadIdx.x;
    const int tx = t & 15, ty = t >> 4;          // 16 x 16 thread grid
    const int i0 = blockIdx.x * 64;

    { // load A band: As[k][i] = A[k*N + i0 + i], float4 coalesced
        const float4* Ag = (const float4*)(A + i0);
#pragma unroll
        for (int l = 0; l < 8; l++) {
            int idx4 = l * 256 + t;
            int k = idx4 >> 4, i4 = idx4 & 15;
            float4 v = Ag[k * (NTOK / 4) + i4];
            *(float4*)&As[k][i4 * 4] = v;
        }
    }
    __syncthreads();

    float rowacc[4] = {0.f, 0.f, 0.f, 0.f};

    for (int jt = 0; jt < 64; jt++) {
        const int j0 = jt * 64;
        float acc[4][4] = {};
        const float4* Bg = (const float4*)(Bm + j0 + tx * 4);
#pragma unroll 8
        for (int k = 0; k < 128; k++) {
            float4 a  = *(const float4*)&As[k][ty * 4];
            float4 bv = Bg[k * (NTOK / 4)];
            acc[0][0] += a.x * bv.x; acc[0][1] += a.x * bv.y; acc[0][2] += a.x * bv.z; acc[0][3] += a.x * bv.w;
            acc[1][0] += a.y * bv.x; acc[1][1] += a.y * bv.y; acc[1][2] += a.y * bv.z; acc[1][3] += a.y * bv.w;
            acc[2][0] += a.z * bv.x; acc[2][1] += a.z * bv.y; acc[2][2] += a.z * bv.z; acc[2][3] += a.z * bv.w;
            acc[3][0] += a.w * bv.x; acc[3][1] += a.w * bv.y; acc[3][2] += a.w * bv.z; acc[3][3] += a.w * bv.w;
        }
#pragma unroll
        for (int r = 0; r < 4; r++) {
            rowacc[r] += __expf(acc[r][0] * SCALEF) + __expf(acc[r][1] * SCALEF)
                       + __expf(acc[r][2] * SCALEF) + __expf(acc[r][3] * SCALEF);
        }
    }

    // reduce across the 16 tx lanes (within each 16-lane group of the wave)
#pragma unroll
    for (int r = 0; r < 4; r++) {
        float v = rowacc[r];
        v += __shfl_xor(v, 1);
        v += __shfl_xor(v, 2);
        v += __shfl_xor(v, 4);
        v += __shfl_xor(v, 8);
        rowacc[r] = v;
    }
    if (tx == 0) {
#pragma unroll
        for (int r = 0; r < 4; r++) zout[i0 + ty * 4 + r] = rowacc[r];
    }
}

// ---------------------------------------------------------------------------
// K2: weighted — out[i][d] = sum_j exp(scale*A_i.B_j) / W_j * A_j[d]
// mode 0 (out_p): A=rp, B=ri, W=Z (col sums);  mode 1 (out_i): A=ri, B=rp,
// W=z (row sums). Values matrix C == A in both modes.
// Per block: 64-row band, 128-wide output held in registers (4x8 frag/thread),
// loop over 64 j-tiles: GEMM1 (S tile) -> exp/W -> E^T via LDS -> GEMM2.
// LDS: As 32KB + Cs 32KB + EsT 16KB = 80KB -> 2 blocks/CU.
// ---------------------------------------------------------------------------
__global__ __launch_bounds__(256) void attn_kernel(const float* __restrict__ pf,
                                                   const float* __restrict__ ri,
                                                   const float* __restrict__ zrow,
                                                   const float* __restrict__ zcol,
                                                   float* __restrict__ fus)
{
    __shared__ float As [128][64];   // [k][i]   32 KB
    __shared__ float Cs [64][128];   // [j][d]   32 KB
    __shared__ float EsT[64][64];    // [j][i]   16 KB

    const int b    = blockIdx.y;
    const int mode = blockIdx.z;
    const float* A  = (mode == 0 ? pf : ri) + b * PCH * NTOK;
    const float* Bm = (mode == 0 ? ri : pf) + b * PCH * NTOK;
    const float* W  = (mode == 0 ? zcol : zrow) + b * NTOK;

    const int t  = threadIdx.x;
    const int tx = t & 15, ty = t >> 4;
    const int i0 = blockIdx.x * 64;

    { // load A band
        const float4* Ag = (const float4*)(A + i0);
#pragma unroll
        for (int l = 0; l < 8; l++) {
            int idx4 = l * 256 + t;
            int k = idx4 >> 4, i4 = idx4 & 15;
            float4 v = Ag[k * (NTOK / 4) + i4];
            *(float4*)&As[k][i4 * 4] = v;
        }
    }
    __syncthreads();

    float out[4][8] = {};

    for (int jt = 0; jt < 64; jt++) {
        const int j0 = jt * 64;

        // ---- GEMM1: S fragment (4 rows x 4 cols per thread), K = 128
        float acc[4][4] = {};
        const float4* Bg = (const float4*)(Bm + j0 + tx * 4);
#pragma unroll 8
        for (int k = 0; k < 128; k++) {
            float4 a  = *(const float4*)&As[k][ty * 4];
            float4 bv = Bg[k * (NTOK / 4)];
            acc[0][0] += a.x * bv.x; acc[0][1] += a.x * bv.y; acc[0][2] += a.x * bv.z; acc[0][3] += a.x * bv.w;
            acc[1][0] += a.y * bv.x; acc[1][1] += a.y * bv.y; acc[1][2] += a.y * bv.z; acc[1][3] += a.y * bv.w;
            acc[2][0] += a.z * bv.x; acc[2][1] += a.z * bv.y; acc[2][2] += a.z * bv.z; acc[2][3] += a.z * bv.w;
            acc[3][0] += a.w * bv.x; acc[3][1] += a.w * bv.y; acc[3][2] += a.w * bv.z; acc[3][3] += a.w * bv.w;
        }

        // ---- weights: E = exp(S*scale)/W_j, stored transposed EsT[j][i]
        {
            float4 wv = *(const float4*)&W[j0 + tx * 4];
            float wr[4] = {1.f / wv.x, 1.f / wv.y, 1.f / wv.z, 1.f / wv.w};
#pragma unroll
            for (int c = 0; c < 4; c++) {
                float4 ev;
                ev.x = __expf(acc[0][c] * SCALEF) * wr[c];
                ev.y = __expf(acc[1][c] * SCALEF) * wr[c];
                ev.z = __expf(acc[2][c] * SCALEF) * wr[c];
                ev.w = __expf(acc[3][c] * SCALEF) * wr[c];
                *(float4*)&EsT[tx * 4 + c][ty * 4] = ev;
            }
        }

        // ---- load C tile (values = A rows j0..j0+63), transpose into Cs[j][d]
        {
            const float4* Cg = (const float4*)(A + j0);
#pragma unroll
            for (int l = 0; l < 8; l++) {
                int idx4 = l * 256 + t;
                int d = idx4 >> 4, j4 = idx4 & 15;
                float4 v = Cg[d * (NTOK / 4) + j4];
                Cs[j4 * 4 + 0][d] = v.x;
                Cs[j4 * 4 + 1][d] = v.y;
                Cs[j4 * 4 + 2][d] = v.z;
                Cs[j4 * 4 + 3][d] = v.w;
            }
        }
        __syncthreads();

        // ---- GEMM2: out[4][8] += E^T-column * C rows
#pragma unroll 8
        for (int jj = 0; jj < 64; jj++) {
            float4 e  = *(const float4*)&EsT[jj][ty * 4];
            float4 cl = *(const float4*)&Cs[jj][tx * 8];
            float4 ch = *(const float4*)&Cs[jj][tx * 8 + 4];
            out[0][0] += e.x * cl.x; out[0][1] += e.x * cl.y; out[0][2] += e.x * cl.z; out[0][3] += e.x * cl.w;
            out[0][4] += e.x * ch.x; out[0][5] += e.x * ch.y; out[0][6] += e.x * ch.z; out[0][7] += e.x * ch.w;
            out[1][0] += e.y * cl.x; out[1][1] += e.y * cl.y; out[1][2] += e.y * cl.z; out[1][3] += e.y * cl.w;
            out[1][4] += e.y * ch.x; out[1][5] += e.y * ch.y; out[1][6] += e.y * ch.z; out[1][7] += e.y * ch.w;
            out[2][0] += e.z * cl.x; out[2][1] += e.z * cl.y; out[2][2] += e.z * cl.z; out[2][3] += e.z * cl.w;
            out[2][4] += e.z * ch.x; out[2][5] += e.z * ch.y; out[2][6] += e.z * ch.z; out[2][7] += e.z * ch.w;
            out[3][0] += e.w * cl.x; out[3][1] += e.w * cl.y; out[3][2] += e.w * cl.z; out[3][3] += e.w * cl.w;
            out[3][4] += e.w * ch.x; out[3][5] += e.w * ch.y; out[3][6] += e.w * ch.z; out[3][7] += e.w * ch.w;
        }
        __syncthreads();
    }

    // ---- write fusion buffer: fus[b][n][mode*128 + d]
    float* fo = fus + (b * NTOK + i0) * 256 + mode * 128 + tx * 8;
#pragma unroll
    for (int r = 0; r < 4; r++) {
        float4 lo = {out[r][0], out[r][1], out[r][2], out[r][3]};
        float4 hi = {out[r][4], out[r][5], out[r][6], out[r][7]};
        *(float4*)&fo[(ty * 4 + r) * 256 + 0] = lo;
        *(float4*)&fo[(ty * 4 + r) * 256 + 4] = hi;
    }
}

// ---------------------------------------------------------------------------
// K3: 1x1 conv (256 -> 128) + BN(eval) + ReLU.
// block = 256 threads = 64 n x 4 o-groups (32 o each). conv_w reads are
// wave-uniform -> scalar loads; fus rows live in L1 across the c loop.
// ---------------------------------------------------------------------------
__global__ __launch_bounds__(256) void conv_kernel(const float* __restrict__ fus,
                                                   const float* __restrict__ cw,
                                                   const float* __restrict__ cb,
                                                   const float* __restrict__ g,
                                                   const float* __restrict__ be,
                                                   const float* __restrict__ mu,
                                                   const float* __restrict__ var,
                                                   float* __restrict__ out)
{
    const int b  = blockIdx.y;
    const int t  = threadIdx.x;
    const int n  = blockIdx.x * 64 + (t & 63);
    const int og = t >> 6;                       // wave-uniform
    const float* fr = fus + (b * NTOK + n) * 256;

    float acc[32] = {};
    for (int c = 0; c < 256; c++) {
        const float v = fr[c];
#pragma unroll
        for (int oo = 0; oo < 32; oo++)
            acc[oo] += cw[(og * 32 + oo) * 256 + c] * v;
    }
#pragma unroll
    for (int oo = 0; oo < 32; oo++) {
        const int o = og * 32 + oo;
        const float s  = g[o] * rsqrtf(var[o] + 1e-5f);
        const float b0 = be[o] + (cb[o] - mu[o]) * s;
        float y = acc[oo] * s + b0;
        out[(b * OCH + o) * NTOK + n] = fmaxf(y, 0.f);
    }
}

// ---------------------------------------------------------------------------
extern "C" void kernel_launch(void* const* d_in, const int* in_sizes, int n_in,
                              void* d_out, int out_size, void* d_ws, size_t ws_size,
                              hipStream_t stream)
{
    const float* pf   = (const float*)d_in[0];  // point_features [B,128,N]
    const float* img  = (const float*)d_in[1];  // img_features   [B,256,N]
    const float* fc2w = (const float*)d_in[2];  // [128,256]
    const float* fc2b = (const float*)d_in[3];  // [128]
    const float* cw   = (const float*)d_in[4];  // [128,256]
    const float* cb   = (const float*)d_in[5];  // [128]
    const float* g    = (const float*)d_in[6];
    const float* be   = (const float*)d_in[7];
    const float* mu   = (const float*)d_in[8];
    const float* var  = (const float*)d_in[9];
    float* out = (float*)d_out;

    float* ws   = (float*)d_ws;
    float* ri   = ws;                       // B*128*N        = 1,048,576 f
    float* zrow = ri   + NB * PCH * NTOK;   // B*N            =     8,192 f
    float* zcol = zrow + NB * NTOK;         // B*N            =     8,192 f
    float* fus  = zcol + NB * NTOK;         // B*N*256        = 2,097,152 f
                                            // total ~12.1 MB of d_ws

    fc2_kernel  <<<dim3(NTOK / 64, NB),    256, 0, stream>>>(img, fc2w, fc2b, ri);
    stats_kernel<<<dim3(NTOK / 64, NB, 2), 256, 0, stream>>>(pf, ri, zrow, zcol);
    attn_kernel <<<dim3(NTOK / 64, NB, 2), 256, 0, stream>>>(pf, ri, zrow, zcol, fus);
    conv_kernel <<<dim3(NTOK / 64, NB),    256, 0, stream>>>(fus, cw, cb, g, be, mu, var, out);
}

// Round 2
// 596.433 us; speedup vs baseline: 2.4784x; 2.4784x over previous
//
#include <hip/hip_runtime.h>
#include <math.h>

// Problem constants
#define NTOK 4096
#define PCH  128
#define ICH  256
#define OCH  128
#define NB   2
#define SCALEF 0.08838834764831845f   // 1/sqrt(128)

typedef __bf16 bf16_t;
typedef __attribute__((ext_vector_type(8))) __bf16 bf16x8;
typedef __attribute__((ext_vector_type(4))) __bf16 bf16x4;
typedef __attribute__((ext_vector_type(4))) float floatx4;

#define LDK 136   // padded row length (bf16 elems) for k=128 tiles: 272 B, breaks 256B stride
#define LDJ 72    // padded row length for j=64 tiles: 144 B

// ---------------------------------------------------------------------------
// K0: pack pf (f32 channel-major) -> pfC bf16 channel-major + pfT bf16 token-major
// ---------------------------------------------------------------------------
__global__ __launch_bounds__(256) void pack_pf(const float* __restrict__ pf,
                                               bf16_t* __restrict__ pfC,
                                               bf16_t* __restrict__ pfT)
{
    __shared__ float Ls[64][65];
    const int t = threadIdx.x;
    const int n0 = blockIdx.x * 64, d0 = blockIdx.y * 64, b = blockIdx.z;
    const float* src = pf + ((size_t)(b * PCH + d0)) * NTOK + n0;
#pragma unroll
    for (int p = 0; p < 4; p++) {
        int d = p * 16 + (t >> 4), c = t & 15;
        float4 v = *(const float4*)&src[d * NTOK + c * 4];
        Ls[d][c * 4 + 0] = v.x; Ls[d][c * 4 + 1] = v.y;
        Ls[d][c * 4 + 2] = v.z; Ls[d][c * 4 + 3] = v.w;
        bf16x4 o = { (bf16_t)v.x, (bf16_t)v.y, (bf16_t)v.z, (bf16_t)v.w };
        *(bf16x4*)&pfC[((size_t)(b * PCH + d0 + d)) * NTOK + n0 + c * 4] = o;
    }
    __syncthreads();
#pragma unroll
    for (int p = 0; p < 2; p++) {
        int n = p * 32 + (t >> 3), c = t & 7;
        bf16x8 o;
#pragma unroll
        for (int k = 0; k < 8; k++) o[k] = (bf16_t)Ls[c * 8 + k][n];
        *(bf16x8*)&pfT[((size_t)(b * NTOK + n0 + n)) * PCH + d0 + c * 8] = o;
    }
}

// ---------------------------------------------------------------------------
// K1: fc2 — ri = fc2(img); emits bf16 channel-major riC + token-major riT
// ---------------------------------------------------------------------------
__global__ __launch_bounds__(256) void fc2_kernel(const float* __restrict__ img,
                                                  const float* __restrict__ w,
                                                  const float* __restrict__ bias,
                                                  bf16_t* __restrict__ riC,
                                                  bf16_t* __restrict__ riT)
{
    const int b = blockIdx.y, t = threadIdx.x;
    const int n = blockIdx.x * 64 + (t & 63);
    const int pg = t >> 6;                        // wave-uniform
    const float* imgb = img + (size_t)b * ICH * NTOK;
    float acc[32];
#pragma unroll
    for (int pp = 0; pp < 32; pp++) acc[pp] = bias[pg * 32 + pp];
    for (int c = 0; c < ICH; c++) {
        float v = imgb[c * NTOK + n];
#pragma unroll
        for (int pp = 0; pp < 32; pp++)
            acc[pp] += w[(pg * 32 + pp) * ICH + c] * v;
    }
#pragma unroll
    for (int pp = 0; pp < 32; pp++)
        riC[((size_t)(b * PCH + pg * 32 + pp)) * NTOK + n] = (bf16_t)acc[pp];
#pragma unroll
    for (int c8 = 0; c8 < 4; c8++) {
        bf16x8 v;
#pragma unroll
        for (int k = 0; k < 8; k++) v[k] = (bf16_t)acc[c8 * 8 + k];
        *(bf16x8*)&riT[((size_t)(b * NTOK + n)) * PCH + pg * 32 + c8 * 8] = v;
    }
}

// ---------------------------------------------------------------------------
// K2: stats — zout[i] = 1 / sum_j exp(scale * A_i . B_j)   (reciprocal stored)
// mode0: A=pf,B=ri (row sums); mode1: A=ri,B=pf (col sums). MFMA 16x16x32 bf16.
// i-band 64/block; j tiles of 64; wave w owns j-slice w*16..w*16+15.
// ---------------------------------------------------------------------------
__global__ __launch_bounds__(256, 2) void stats_mfma(const bf16_t* __restrict__ pfT,
                                                     const bf16_t* __restrict__ riT,
                                                     float* __restrict__ zr,
                                                     float* __restrict__ zc)
{
    __shared__ bf16_t As[64 * LDK];
    __shared__ bf16_t Bs[64 * LDK];
    __shared__ float  Zp[4][64];
    const int b = blockIdx.y, mode = blockIdx.z, t = threadIdx.x;
    const bf16_t* At = (mode == 0 ? pfT : riT) + (size_t)b * NTOK * PCH;
    const bf16_t* Bt = (mode == 0 ? riT : pfT) + (size_t)b * NTOK * PCH;
    float* zout = (mode == 0 ? zr : zc) + (size_t)b * NTOK;
    const int lane = t & 63, w = t >> 6, tx = lane & 15, q = lane >> 4;
    const int i0 = blockIdx.x * 64;

#pragma unroll
    for (int p = 0; p < 4; p++) {                       // stage A band [64 i][128 k]
        int i = p * 16 + (t >> 4), c = t & 15;
        *(uint4*)&As[i * LDK + c * 8] = *(const uint4*)&At[((size_t)(i0 + i)) * PCH + c * 8];
    }
    __syncthreads();
    bf16x8 af[4][4];                                    // hoisted A fragments
#pragma unroll
    for (int mt = 0; mt < 4; mt++)
#pragma unroll
        for (int s = 0; s < 4; s++)
            af[mt][s] = *(bf16x8*)&As[(mt * 16 + tx) * LDK + s * 32 + q * 8];

    float racc[4][4] = {};
    for (int jt = 0; jt < 64; jt++) {
        const int j0 = jt * 64;
        __syncthreads();
#pragma unroll
        for (int p = 0; p < 4; p++) {                   // stage B tile [64 j][128 k]
            int j = p * 16 + (t >> 4), c = t & 15;
            *(uint4*)&Bs[j * LDK + c * 8] = *(const uint4*)&Bt[((size_t)(j0 + j)) * PCH + c * 8];
        }
        __syncthreads();
        bf16x8 bf[4];
#pragma unroll
        for (int s = 0; s < 4; s++)
            bf[s] = *(bf16x8*)&Bs[(w * 16 + tx) * LDK + s * 32 + q * 8];
#pragma unroll
        for (int mt = 0; mt < 4; mt++) {
            floatx4 sacc = {0.f, 0.f, 0.f, 0.f};
#pragma unroll
            for (int s = 0; s < 4; s++)
                sacc = __builtin_amdgcn_mfma_f32_16x16x32_bf16(af[mt][s], bf[s], sacc, 0, 0, 0);
#pragma unroll
            for (int r = 0; r < 4; r++)
                racc[mt][r] += __expf(sacc[r] * SCALEF);
        }
    }
#pragma unroll
    for (int mt = 0; mt < 4; mt++)
#pragma unroll
        for (int r = 0; r < 4; r++) {
            float v = racc[mt][r];
            v += __shfl_xor(v, 1); v += __shfl_xor(v, 2);
            v += __shfl_xor(v, 4); v += __shfl_xor(v, 8);
            racc[mt][r] = v;
        }
    if (tx == 0) {
#pragma unroll
        for (int mt = 0; mt < 4; mt++)
#pragma unroll
            for (int r = 0; r < 4; r++)
                Zp[w][mt * 16 + q * 4 + r] = racc[mt][r];
    }
    __syncthreads();
    if (t < 64) {
        float s = Zp[0][t] + Zp[1][t] + Zp[2][t] + Zp[3][t];
        zout[i0 + t] = 1.0f / s;
    }
}

// ---------------------------------------------------------------------------
// K3: attn — out[i][d] = sum_j exp(scale*A_i.B_j) * wrec[j] * A_j[d]
// GEMM1 j-split across waves (wave owns 16 j cols); exp * wrec -> Es (C->A
// layout round-trip through LDS); GEMM2 d-split (wave owns 32 d), V-fragments
// read direct from L2-hot channel-major global.
// ---------------------------------------------------------------------------
__global__ __launch_bounds__(256, 2) void attn_mfma(const bf16_t* __restrict__ pfT,
                                                    const bf16_t* __restrict__ riT,
                                                    const bf16_t* __restrict__ pfC,
                                                    const bf16_t* __restrict__ riC,
                                                    const float* __restrict__ zrrec,
                                                    const float* __restrict__ zcrec,
                                                    float* __restrict__ fus)
{
    __shared__ bf16_t As[64 * LDK];
    __shared__ bf16_t Bs[64 * LDK];
    __shared__ bf16_t Es[64 * LDJ];
    const int b = blockIdx.y, mode = blockIdx.z, t = threadIdx.x;
    const bf16_t* At = (mode == 0 ? pfT : riT) + (size_t)b * NTOK * PCH;
    const bf16_t* Bt = (mode == 0 ? riT : pfT) + (size_t)b * NTOK * PCH;
    const bf16_t* Vc = (mode == 0 ? pfC : riC) + (size_t)b * PCH * NTOK;
    const float* wrec = (mode == 0 ? zcrec : zrrec) + (size_t)b * NTOK;
    const int lane = t & 63, w = t >> 6, tx = lane & 15, q = lane >> 4;
    const int i0 = blockIdx.x * 64;

#pragma unroll
    for (int p = 0; p < 4; p++) {                       // stage A band
        int i = p * 16 + (t >> 4), c = t & 15;
        *(uint4*)&As[i * LDK + c * 8] = *(const uint4*)&At[((size_t)(i0 + i)) * PCH + c * 8];
    }
    __syncthreads();
    bf16x8 af[4][4];
#pragma unroll
    for (int mt = 0; mt < 4; mt++)
#pragma unroll
        for (int s = 0; s < 4; s++)
            af[mt][s] = *(bf16x8*)&As[(mt * 16 + tx) * LDK + s * 32 + q * 8];

    floatx4 outacc[4][2];
#pragma unroll
    for (int mt = 0; mt < 4; mt++)
#pragma unroll
        for (int nt = 0; nt < 2; nt++)
            outacc[mt][nt] = (floatx4){0.f, 0.f, 0.f, 0.f};

    for (int jt = 0; jt < 64; jt++) {
        const int j0 = jt * 64;
        __syncthreads();
#pragma unroll
        for (int p = 0; p < 4; p++) {                   // stage B tile
            int j = p * 16 + (t >> 4), c = t & 15;
            *(uint4*)&Bs[j * LDK + c * 8] = *(const uint4*)&Bt[((size_t)(j0 + j)) * PCH + c * 8];
        }
        __syncthreads();

        // ---- GEMM1 (wave's 16-j slice), exp, normalized weights -> Es
        bf16x8 bf[4];
#pragma unroll
        for (int s = 0; s < 4; s++)
            bf[s] = *(bf16x8*)&Bs[(w * 16 + tx) * LDK + s * 32 + q * 8];
        const float wr = wrec[j0 + w * 16 + tx];
#pragma unroll
        for (int mt = 0; mt < 4; mt++) {
            floatx4 sacc = {0.f, 0.f, 0.f, 0.f};
#pragma unroll
            for (int s = 0; s < 4; s++)
                sacc = __builtin_amdgcn_mfma_f32_16x16x32_bf16(af[mt][s], bf[s], sacc, 0, 0, 0);
#pragma unroll
            for (int r = 0; r < 4; r++) {
                float e = __expf(sacc[r] * SCALEF) * wr;
                Es[(mt * 16 + q * 4 + r) * LDJ + w * 16 + tx] = (bf16_t)e;
            }
        }
        __syncthreads();

        // ---- GEMM2: wave's 32-d slice, K = 64 (this j-tile)
        bf16x8 ef[4][2];
#pragma unroll
        for (int mt = 0; mt < 4; mt++)
#pragma unroll
            for (int s = 0; s < 2; s++)
                ef[mt][s] = *(bf16x8*)&Es[(mt * 16 + tx) * LDJ + s * 32 + q * 8];
#pragma unroll
        for (int nt = 0; nt < 2; nt++)
#pragma unroll
            for (int s = 0; s < 2; s++) {
                bf16x8 vf = *(const bf16x8*)&Vc[((size_t)(w * 32 + nt * 16 + tx)) * NTOK + j0 + s * 32 + q * 8];
#pragma unroll
                for (int mt = 0; mt < 4; mt++)
                    outacc[mt][nt] = __builtin_amdgcn_mfma_f32_16x16x32_bf16(ef[mt][s], vf, outacc[mt][nt], 0, 0, 0);
            }
    }

    // ---- epilogue: fus[b][i][mode*128 + d]
    float* fo = fus + ((size_t)(b * NTOK + i0)) * 256 + mode * 128 + w * 32;
#pragma unroll
    for (int mt = 0; mt < 4; mt++)
#pragma unroll
        for (int nt = 0; nt < 2; nt++)
#pragma unroll
            for (int r = 0; r < 4; r++)
                fo[(mt * 16 + q * 4 + r) * 256 + nt * 16 + tx] = outacc[mt][nt][r];
}

// ---------------------------------------------------------------------------
// K4: 1x1 conv (256 -> 128) + BN(eval) + ReLU
// ---------------------------------------------------------------------------
__global__ __launch_bounds__(256) void conv_kernel(const float* __restrict__ fus,
                                                   const float* __restrict__ cw,
                                                   const float* __restrict__ cb,
                                                   const float* __restrict__ g,
                                                   const float* __restrict__ be,
                                                   const float* __restrict__ mu,
                                                   const float* __restrict__ var,
                                                   float* __restrict__ out)
{
    const int b = blockIdx.y, t = threadIdx.x;
    const int n = blockIdx.x * 64 + (t & 63);
    const int og = t >> 6;                        // wave-uniform
    const float* fr = fus + ((size_t)(b * NTOK + n)) * 256;

    float acc[32] = {};
    for (int c4 = 0; c4 < 64; c4++) {
        float4 v = *(const float4*)&fr[c4 * 4];
#pragma unroll
        for (int oo = 0; oo < 32; oo++) {
            const float* wr = &cw[(og * 32 + oo) * 256 + c4 * 4];
            acc[oo] += wr[0] * v.x + wr[1] * v.y + wr[2] * v.z + wr[3] * v.w;
        }
    }
#pragma unroll
    for (int oo = 0; oo < 32; oo++) {
        const int o = og * 32 + oo;
        const float s  = g[o] * rsqrtf(var[o] + 1e-5f);
        const float b0 = be[o] + (cb[o] - mu[o]) * s;
        float y = acc[oo] * s + b0;
        out[((size_t)(b * OCH + o)) * NTOK + n] = fmaxf(y, 0.f);
    }
}

// ---------------------------------------------------------------------------
extern "C" void kernel_launch(void* const* d_in, const int* in_sizes, int n_in,
                              void* d_out, int out_size, void* d_ws, size_t ws_size,
                              hipStream_t stream)
{
    const float* pf   = (const float*)d_in[0];
    const float* img  = (const float*)d_in[1];
    const float* fc2w = (const float*)d_in[2];
    const float* fc2b = (const float*)d_in[3];
    const float* cw   = (const float*)d_in[4];
    const float* cb   = (const float*)d_in[5];
    const float* g    = (const float*)d_in[6];
    const float* be   = (const float*)d_in[7];
    const float* mu   = (const float*)d_in[8];
    const float* var  = (const float*)d_in[9];
    float* out = (float*)d_out;

    // workspace layout (16B-aligned chunks), ~16.1 MB total
    bf16_t* pfC = (bf16_t*)d_ws;                              // 2 MB
    bf16_t* pfT = pfC + (size_t)NB * PCH * NTOK;              // 2 MB
    bf16_t* riC = pfT + (size_t)NB * NTOK * PCH;              // 2 MB
    bf16_t* riT = riC + (size_t)NB * PCH * NTOK;              // 2 MB
    float* zrrec = (float*)(riT + (size_t)NB * NTOK * PCH);   // 32 KB
    float* zcrec = zrrec + NB * NTOK;                         // 32 KB
    float* fus   = zcrec + NB * NTOK;                         // 8 MB

    pack_pf    <<<dim3(64, 2, NB),  256, 0, stream>>>(pf, pfC, pfT);
    fc2_kernel <<<dim3(64, NB),     256, 0, stream>>>(img, fc2w, fc2b, riC, riT);
    stats_mfma <<<dim3(64, NB, 2),  256, 0, stream>>>(pfT, riT, zrrec, zcrec);
    attn_mfma  <<<dim3(64, NB, 2),  256, 0, stream>>>(pfT, riT, pfC, riC, zrrec, zcrec, fus);
    conv_kernel<<<dim3(64, NB),     256, 0, stream>>>(fus, cw, cb, g, be, mu, var, out);
}

// Round 3
// 374.521 us; speedup vs baseline: 3.9469x; 1.5925x over previous
//
#include <hip/hip_runtime.h>
#include <math.h>

// Problem constants
#define NTOK 4096
#define PCH  128
#define ICH  256
#define OCH  128
#define NB   2
#define SCALEF 0.08838834764831845f   // 1/sqrt(128)

typedef __bf16 bf16_t;
typedef __attribute__((ext_vector_type(8))) __bf16 bf16x8;
typedef __attribute__((ext_vector_type(4))) __bf16 bf16x4;
typedef __attribute__((ext_vector_type(4))) float floatx4;

#define LDK 136   // padded row length (bf16 elems) for k=128 tiles
#define LDJ 72    // padded row length for j=64 tiles

// ---------------------------------------------------------------------------
// K0: pack pf (f32 channel-major) -> pfC bf16 channel-major + pfT bf16 token-major
// ---------------------------------------------------------------------------
__global__ __launch_bounds__(256) void pack_pf(const float* __restrict__ pf,
                                               bf16_t* __restrict__ pfC,
                                               bf16_t* __restrict__ pfT)
{
    __shared__ float Ls[64][65];
    const int t = threadIdx.x;
    const int n0 = blockIdx.x * 64, d0 = blockIdx.y * 64, b = blockIdx.z;
    const float* src = pf + ((size_t)(b * PCH + d0)) * NTOK + n0;
#pragma unroll
    for (int p = 0; p < 4; p++) {
        int d = p * 16 + (t >> 4), c = t & 15;
        float4 v = *(const float4*)&src[d * NTOK + c * 4];
        Ls[d][c * 4 + 0] = v.x; Ls[d][c * 4 + 1] = v.y;
        Ls[d][c * 4 + 2] = v.z; Ls[d][c * 4 + 3] = v.w;
        bf16x4 o = { (bf16_t)v.x, (bf16_t)v.y, (bf16_t)v.z, (bf16_t)v.w };
        *(bf16x4*)&pfC[((size_t)(b * PCH + d0 + d)) * NTOK + n0 + c * 4] = o;
    }
    __syncthreads();
#pragma unroll
    for (int p = 0; p < 2; p++) {
        int n = p * 32 + (t >> 3), c = t & 7;
        bf16x8 o;
#pragma unroll
        for (int k = 0; k < 8; k++) o[k] = (bf16_t)Ls[c * 8 + k][n];
        *(bf16x8*)&pfT[((size_t)(b * NTOK + n0 + n)) * PCH + d0 + c * 8] = o;
    }
}

// ---------------------------------------------------------------------------
// K1: fc2 — ri[b][p][n] = sum_c img[b][c][n]*w[p][c] + bias[p]
// v2: 512 blocks (2/CU), 8 outputs/thread (8:1 FMA:load), c unrolled x4 with
// float4 weight loads. Emits bf16 channel-major riC + token-major riT.
// ---------------------------------------------------------------------------
__global__ __launch_bounds__(256) void fc2_kernel(const float* __restrict__ img,
                                                  const float* __restrict__ w,
                                                  const float* __restrict__ bias,
                                                  bf16_t* __restrict__ riC,
                                                  bf16_t* __restrict__ riT)
{
    const int b = blockIdx.z, t = threadIdx.x;
    const int n = blockIdx.x * 64 + (t & 63);
    const int pbase = blockIdx.y * 32 + (t >> 6) * 8;   // wave-uniform
    const float* imgb = img + (size_t)b * ICH * NTOK + n;

    float acc[8];
#pragma unroll
    for (int pp = 0; pp < 8; pp++) acc[pp] = bias[pbase + pp];

    for (int c = 0; c < ICH; c += 4) {
        float v0 = imgb[(c + 0) * NTOK];
        float v1 = imgb[(c + 1) * NTOK];
        float v2 = imgb[(c + 2) * NTOK];
        float v3 = imgb[(c + 3) * NTOK];
#pragma unroll
        for (int pp = 0; pp < 8; pp++) {
            float4 wv = *(const float4*)&w[(pbase + pp) * ICH + c];
            acc[pp] += wv.x * v0 + wv.y * v1 + wv.z * v2 + wv.w * v3;
        }
    }

#pragma unroll
    for (int pp = 0; pp < 8; pp++)
        riC[((size_t)(b * PCH + pbase + pp)) * NTOK + n] = (bf16_t)acc[pp];
    bf16x8 tv;
#pragma unroll
    for (int pp = 0; pp < 8; pp++) tv[pp] = (bf16_t)acc[pp];
    *(bf16x8*)&riT[((size_t)(b * NTOK + n)) * PCH + pbase] = tv;
}

// ---------------------------------------------------------------------------
// K2: stats — zout[i] = 1 / sum_j exp(scale * A_i . B_j)   (reciprocal stored)
// ---------------------------------------------------------------------------
__global__ __launch_bounds__(256, 2) void stats_mfma(const bf16_t* __restrict__ pfT,
                                                     const bf16_t* __restrict__ riT,
                                                     float* __restrict__ zr,
                                                     float* __restrict__ zc)
{
    __shared__ bf16_t As[64 * LDK];
    __shared__ bf16_t Bs[64 * LDK];
    __shared__ float  Zp[4][64];
    const int b = blockIdx.y, mode = blockIdx.z, t = threadIdx.x;
    const bf16_t* At = (mode == 0 ? pfT : riT) + (size_t)b * NTOK * PCH;
    const bf16_t* Bt = (mode == 0 ? riT : pfT) + (size_t)b * NTOK * PCH;
    float* zout = (mode == 0 ? zr : zc) + (size_t)b * NTOK;
    const int lane = t & 63, w = t >> 6, tx = lane & 15, q = lane >> 4;
    const int i0 = blockIdx.x * 64;

#pragma unroll
    for (int p = 0; p < 4; p++) {
        int i = p * 16 + (t >> 4), c = t & 15;
        *(uint4*)&As[i * LDK + c * 8] = *(const uint4*)&At[((size_t)(i0 + i)) * PCH + c * 8];
    }
    __syncthreads();
    bf16x8 af[4][4];
#pragma unroll
    for (int mt = 0; mt < 4; mt++)
#pragma unroll
        for (int s = 0; s < 4; s++)
            af[mt][s] = *(bf16x8*)&As[(mt * 16 + tx) * LDK + s * 32 + q * 8];

    float racc[4][4] = {};
    for (int jt = 0; jt < 64; jt++) {
        const int j0 = jt * 64;
        __syncthreads();
#pragma unroll
        for (int p = 0; p < 4; p++) {
            int j = p * 16 + (t >> 4), c = t & 15;
            *(uint4*)&Bs[j * LDK + c * 8] = *(const uint4*)&Bt[((size_t)(j0 + j)) * PCH + c * 8];
        }
        __syncthreads();
        bf16x8 bf[4];
#pragma unroll
        for (int s = 0; s < 4; s++)
            bf[s] = *(bf16x8*)&Bs[(w * 16 + tx) * LDK + s * 32 + q * 8];
#pragma unroll
        for (int mt = 0; mt < 4; mt++) {
            floatx4 sacc = {0.f, 0.f, 0.f, 0.f};
#pragma unroll
            for (int s = 0; s < 4; s++)
                sacc = __builtin_amdgcn_mfma_f32_16x16x32_bf16(af[mt][s], bf[s], sacc, 0, 0, 0);
#pragma unroll
            for (int r = 0; r < 4; r++)
                racc[mt][r] += __expf(sacc[r] * SCALEF);
        }
    }
#pragma unroll
    for (int mt = 0; mt < 4; mt++)
#pragma unroll
        for (int r = 0; r < 4; r++) {
            float v = racc[mt][r];
            v += __shfl_xor(v, 1); v += __shfl_xor(v, 2);
            v += __shfl_xor(v, 4); v += __shfl_xor(v, 8);
            racc[mt][r] = v;
        }
    if (tx == 0) {
#pragma unroll
        for (int mt = 0; mt < 4; mt++)
#pragma unroll
            for (int r = 0; r < 4; r++)
                Zp[w][mt * 16 + q * 4 + r] = racc[mt][r];
    }
    __syncthreads();
    if (t < 64) {
        float s = Zp[0][t] + Zp[1][t] + Zp[2][t] + Zp[3][t];
        zout[i0 + t] = 1.0f / s;
    }
}

// ---------------------------------------------------------------------------
// K3: attn — out[i][d] = sum_j exp(scale*A_i.B_j) * wrec[j] * A_j[d]
// ---------------------------------------------------------------------------
__global__ __launch_bounds__(256, 2) void attn_mfma(const bf16_t* __restrict__ pfT,
                                                    const bf16_t* __restrict__ riT,
                                                    const bf16_t* __restrict__ pfC,
                                                    const bf16_t* __restrict__ riC,
                                                    const float* __restrict__ zrrec,
                                                    const float* __restrict__ zcrec,
                                                    float* __restrict__ fus)
{
    __shared__ bf16_t As[64 * LDK];
    __shared__ bf16_t Bs[64 * LDK];
    __shared__ bf16_t Es[64 * LDJ];
    const int b = blockIdx.y, mode = blockIdx.z, t = threadIdx.x;
    const bf16_t* At = (mode == 0 ? pfT : riT) + (size_t)b * NTOK * PCH;
    const bf16_t* Bt = (mode == 0 ? riT : pfT) + (size_t)b * NTOK * PCH;
    const bf16_t* Vc = (mode == 0 ? pfC : riC) + (size_t)b * PCH * NTOK;
    const float* wrec = (mode == 0 ? zcrec : zrrec) + (size_t)b * NTOK;
    const int lane = t & 63, w = t >> 6, tx = lane & 15, q = lane >> 4;
    const int i0 = blockIdx.x * 64;

#pragma unroll
    for (int p = 0; p < 4; p++) {
        int i = p * 16 + (t >> 4), c = t & 15;
        *(uint4*)&As[i * LDK + c * 8] = *(const uint4*)&At[((size_t)(i0 + i)) * PCH + c * 8];
    }
    __syncthreads();
    bf16x8 af[4][4];
#pragma unroll
    for (int mt = 0; mt < 4; mt++)
#pragma unroll
        for (int s = 0; s < 4; s++)
            af[mt][s] = *(bf16x8*)&As[(mt * 16 + tx) * LDK + s * 32 + q * 8];

    floatx4 outacc[4][2];
#pragma unroll
    for (int mt = 0; mt < 4; mt++)
#pragma unroll
        for (int nt = 0; nt < 2; nt++)
            outacc[mt][nt] = (floatx4){0.f, 0.f, 0.f, 0.f};

    for (int jt = 0; jt < 64; jt++) {
        const int j0 = jt * 64;
        __syncthreads();
#pragma unroll
        for (int p = 0; p < 4; p++) {
            int j = p * 16 + (t >> 4), c = t & 15;
            *(uint4*)&Bs[j * LDK + c * 8] = *(const uint4*)&Bt[((size_t)(j0 + j)) * PCH + c * 8];
        }
        __syncthreads();

        bf16x8 bf[4];
#pragma unroll
        for (int s = 0; s < 4; s++)
            bf[s] = *(bf16x8*)&Bs[(w * 16 + tx) * LDK + s * 32 + q * 8];
        const float wr = wrec[j0 + w * 16 + tx];
#pragma unroll
        for (int mt = 0; mt < 4; mt++) {
            floatx4 sacc = {0.f, 0.f, 0.f, 0.f};
#pragma unroll
            for (int s = 0; s < 4; s++)
                sacc = __builtin_amdgcn_mfma_f32_16x16x32_bf16(af[mt][s], bf[s], sacc, 0, 0, 0);
#pragma unroll
            for (int r = 0; r < 4; r++) {
                float e = __expf(sacc[r] * SCALEF) * wr;
                Es[(mt * 16 + q * 4 + r) * LDJ + w * 16 + tx] = (bf16_t)e;
            }
        }
        __syncthreads();

        bf16x8 ef[4][2];
#pragma unroll
        for (int mt = 0; mt < 4; mt++)
#pragma unroll
            for (int s = 0; s < 2; s++)
                ef[mt][s] = *(bf16x8*)&Es[(mt * 16 + tx) * LDJ + s * 32 + q * 8];
#pragma unroll
        for (int nt = 0; nt < 2; nt++)
#pragma unroll
            for (int s = 0; s < 2; s++) {
                bf16x8 vf = *(const bf16x8*)&Vc[((size_t)(w * 32 + nt * 16 + tx)) * NTOK + j0 + s * 32 + q * 8];
#pragma unroll
                for (int mt = 0; mt < 4; mt++)
                    outacc[mt][nt] = __builtin_amdgcn_mfma_f32_16x16x32_bf16(ef[mt][s], vf, outacc[mt][nt], 0, 0, 0);
            }
    }

    float* fo = fus + ((size_t)(b * NTOK + i0)) * 256 + mode * 128 + w * 32;
#pragma unroll
    for (int mt = 0; mt < 4; mt++)
#pragma unroll
        for (int nt = 0; nt < 2; nt++)
#pragma unroll
            for (int r = 0; r < 4; r++)
                fo[(mt * 16 + q * 4 + r) * 256 + nt * 16 + tx] = outacc[mt][nt][r];
}

// ---------------------------------------------------------------------------
// K4: 1x1 conv (256 -> 128) + BN(eval) + ReLU.
// v2: LDS-staged fus tile (coalesced row loads, one wave = one 1KB token row),
// pad 260 so float4 LDS reads spread bank quads; 8 outputs/thread, 512 blocks.
// ---------------------------------------------------------------------------
__global__ __launch_bounds__(256) void conv_kernel(const float* __restrict__ fus,
                                                   const float* __restrict__ cw,
                                                   const float* __restrict__ cb,
                                                   const float* __restrict__ g,
                                                   const float* __restrict__ be,
                                                   const float* __restrict__ mu,
                                                   const float* __restrict__ var,
                                                   float* __restrict__ out)
{
    __shared__ float Ls[64][260];   // 66.6 KB
    const int b = blockIdx.z, t = threadIdx.x;
    const int n0 = blockIdx.x * 64;
    const int obase = blockIdx.y * 32 + (t >> 6) * 8;   // wave-uniform

    const float4* src = (const float4*)(fus + ((size_t)(b * NTOK + n0)) * 256);
#pragma unroll
    for (int it = 0; it < 16; it++) {
        int row = it * 4 + (t >> 6);
        float4 v = src[row * 64 + (t & 63)];
        *(float4*)&Ls[row][(t & 63) * 4] = v;
    }
    __syncthreads();

    const int n = t & 63;
    float acc[8] = {};
    for (int c = 0; c < 256; c += 4) {
        float4 v = *(const float4*)&Ls[n][c];
#pragma unroll
        for (int oo = 0; oo < 8; oo++) {
            float4 wv = *(const float4*)&cw[(obase + oo) * 256 + c];
            acc[oo] += wv.x * v.x + wv.y * v.y + wv.z * v.z + wv.w * v.w;
        }
    }
#pragma unroll
    for (int oo = 0; oo < 8; oo++) {
        const int o = obase + oo;
        const float s  = g[o] * rsqrtf(var[o] + 1e-5f);
        const float b0 = be[o] + (cb[o] - mu[o]) * s;
        float y = acc[oo] * s + b0;
        out[((size_t)(b * OCH + o)) * NTOK + n0 + n] = fmaxf(y, 0.f);
    }
}

// ---------------------------------------------------------------------------
extern "C" void kernel_launch(void* const* d_in, const int* in_sizes, int n_in,
                              void* d_out, int out_size, void* d_ws, size_t ws_size,
                              hipStream_t stream)
{
    const float* pf   = (const float*)d_in[0];
    const float* img  = (const float*)d_in[1];
    const float* fc2w = (const float*)d_in[2];
    const float* fc2b = (const float*)d_in[3];
    const float* cw   = (const float*)d_in[4];
    const float* cb   = (const float*)d_in[5];
    const float* g    = (const float*)d_in[6];
    const float* be   = (const float*)d_in[7];
    const float* mu   = (const float*)d_in[8];
    const float* var  = (const float*)d_in[9];
    float* out = (float*)d_out;

    bf16_t* pfC = (bf16_t*)d_ws;
    bf16_t* pfT = pfC + (size_t)NB * PCH * NTOK;
    bf16_t* riC = pfT + (size_t)NB * NTOK * PCH;
    bf16_t* riT = riC + (size_t)NB * PCH * NTOK;
    float* zrrec = (float*)(riT + (size_t)NB * NTOK * PCH);
    float* zcrec = zrrec + NB * NTOK;
    float* fus   = zcrec + NB * NTOK;

    pack_pf    <<<dim3(64, 2, NB),  256, 0, stream>>>(pf, pfC, pfT);
    fc2_kernel <<<dim3(64, 4, NB),  256, 0, stream>>>(img, fc2w, fc2b, riC, riT);
    stats_mfma <<<dim3(64, NB, 2),  256, 0, stream>>>(pfT, riT, zrrec, zcrec);
    attn_mfma  <<<dim3(64, NB, 2),  256, 0, stream>>>(pfT, riT, pfC, riC, zrrec, zcrec, fus);
    conv_kernel<<<dim3(64, 4, NB),  256, 0, stream>>>(fus, cw, cb, g, be, mu, var, out);
}

// Round 4
// 369.749 us; speedup vs baseline: 3.9978x; 1.0129x over previous
//
#include <hip/hip_runtime.h>
#include <math.h>

// Problem constants
#define NTOK 4096
#define PCH  128
#define ICH  256
#define OCH  128
#define NB   2
#define SCALEF 0.08838834764831845f   // 1/sqrt(128)

typedef __bf16 bf16_t;
typedef __attribute__((ext_vector_type(8))) __bf16 bf16x8;
typedef __attribute__((ext_vector_type(4))) __bf16 bf16x4;
typedef __attribute__((ext_vector_type(4))) float floatx4;

#define LDK 136   // padded row length (bf16 elems) for k=128 tiles
#define LDJ 72    // padded row length for j=64 tiles

// ---------------------------------------------------------------------------
// K-1: zero fus (8 MB) + zsum buffers (64 KB) — contiguous region at ws start.
// 2064 blocks x 256 threads x float4 = 2,113,536 floats exactly.
// ---------------------------------------------------------------------------
__global__ __launch_bounds__(256) void zero_kernel(float4* __restrict__ p)
{
    p[(size_t)blockIdx.x * 256 + threadIdx.x] = float4{0.f, 0.f, 0.f, 0.f};
}

// ---------------------------------------------------------------------------
// K0: pack pf (f32 channel-major) -> pfC bf16 channel-major + pfT bf16 token-major
// ---------------------------------------------------------------------------
__global__ __launch_bounds__(256) void pack_pf(const float* __restrict__ pf,
                                               bf16_t* __restrict__ pfC,
                                               bf16_t* __restrict__ pfT)
{
    __shared__ float Ls[64][65];
    const int t = threadIdx.x;
    const int n0 = blockIdx.x * 64, d0 = blockIdx.y * 64, b = blockIdx.z;
    const float* src = pf + ((size_t)(b * PCH + d0)) * NTOK + n0;
#pragma unroll
    for (int p = 0; p < 4; p++) {
        int d = p * 16 + (t >> 4), c = t & 15;
        float4 v = *(const float4*)&src[d * NTOK + c * 4];
        Ls[d][c * 4 + 0] = v.x; Ls[d][c * 4 + 1] = v.y;
        Ls[d][c * 4 + 2] = v.z; Ls[d][c * 4 + 3] = v.w;
        bf16x4 o = { (bf16_t)v.x, (bf16_t)v.y, (bf16_t)v.z, (bf16_t)v.w };
        *(bf16x4*)&pfC[((size_t)(b * PCH + d0 + d)) * NTOK + n0 + c * 4] = o;
    }
    __syncthreads();
#pragma unroll
    for (int p = 0; p < 2; p++) {
        int n = p * 32 + (t >> 3), c = t & 7;
        bf16x8 o;
#pragma unroll
        for (int k = 0; k < 8; k++) o[k] = (bf16_t)Ls[c * 8 + k][n];
        *(bf16x8*)&pfT[((size_t)(b * NTOK + n0 + n)) * PCH + d0 + c * 8] = o;
    }
}

// ---------------------------------------------------------------------------
// K1: fc2 — ri[b][p][n] = sum_c img[b][c][n]*w[p][c] + bias[p]
// ---------------------------------------------------------------------------
__global__ __launch_bounds__(256) void fc2_kernel(const float* __restrict__ img,
                                                  const float* __restrict__ w,
                                                  const float* __restrict__ bias,
                                                  bf16_t* __restrict__ riC,
                                                  bf16_t* __restrict__ riT)
{
    const int b = blockIdx.z, t = threadIdx.x;
    const int n = blockIdx.x * 64 + (t & 63);
    const int pbase = blockIdx.y * 32 + (t >> 6) * 8;   // wave-uniform
    const float* imgb = img + (size_t)b * ICH * NTOK + n;

    float acc[8];
#pragma unroll
    for (int pp = 0; pp < 8; pp++) acc[pp] = bias[pbase + pp];

    for (int c = 0; c < ICH; c += 4) {
        float v0 = imgb[(c + 0) * NTOK];
        float v1 = imgb[(c + 1) * NTOK];
        float v2 = imgb[(c + 2) * NTOK];
        float v3 = imgb[(c + 3) * NTOK];
#pragma unroll
        for (int pp = 0; pp < 8; pp++) {
            float4 wv = *(const float4*)&w[(pbase + pp) * ICH + c];
            acc[pp] += wv.x * v0 + wv.y * v1 + wv.z * v2 + wv.w * v3;
        }
    }

#pragma unroll
    for (int pp = 0; pp < 8; pp++)
        riC[((size_t)(b * PCH + pbase + pp)) * NTOK + n] = (bf16_t)acc[pp];
    bf16x8 tv;
#pragma unroll
    for (int pp = 0; pp < 8; pp++) tv[pp] = (bf16_t)acc[pp];
    *(bf16x8*)&riT[((size_t)(b * NTOK + n)) * PCH + pbase] = tv;
}

// ---------------------------------------------------------------------------
// K2: stats — zsum[i] += sum_{j in half} exp(scale * A_i . B_j)  (atomicAdd)
// blockIdx.z = mode*2 + jsplit.  2 blocks/CU (grid 512), B-tile reg prefetch.
// ---------------------------------------------------------------------------
__global__ __launch_bounds__(256, 2) void stats_mfma(const bf16_t* __restrict__ pfT,
                                                     const bf16_t* __restrict__ riT,
                                                     float* __restrict__ zr,
                                                     float* __restrict__ zc)
{
    __shared__ bf16_t As[64 * LDK];
    __shared__ bf16_t Bs[64 * LDK];
    const int b = blockIdx.y, t = threadIdx.x;
    const int mode = blockIdx.z >> 1, js = blockIdx.z & 1;
    const bf16_t* At = (mode == 0 ? pfT : riT) + (size_t)b * NTOK * PCH;
    const bf16_t* Bt = (mode == 0 ? riT : pfT) + (size_t)b * NTOK * PCH;
    float* zout = (mode == 0 ? zr : zc) + (size_t)b * NTOK;
    const int lane = t & 63, w = t >> 6, tx = lane & 15, q = lane >> 4;
    const int i0 = blockIdx.x * 64;
    const int jbase = js * 2048;
    const int sr = t >> 4, sc = t & 15;          // staging row/col

#pragma unroll
    for (int p = 0; p < 4; p++) {                // stage A band [64 i][128 k]
        int i = p * 16 + sr;
        *(uint4*)&As[i * LDK + sc * 8] = *(const uint4*)&At[((size_t)(i0 + i)) * PCH + sc * 8];
    }
    __syncthreads();
    bf16x8 af[4][4];
#pragma unroll
    for (int mt = 0; mt < 4; mt++)
#pragma unroll
        for (int s = 0; s < 4; s++)
            af[mt][s] = *(bf16x8*)&As[(mt * 16 + tx) * LDK + s * 32 + q * 8];

    // prefetch first B tile into registers
    uint4 breg[4];
#pragma unroll
    for (int p = 0; p < 4; p++)
        breg[p] = *(const uint4*)&Bt[((size_t)(jbase + p * 16 + sr)) * PCH + sc * 8];

    float racc[4][4] = {};
    for (int jt = 0; jt < 32; jt++) {
        __syncthreads();                          // Bs readers from prev iter done
#pragma unroll
        for (int p = 0; p < 4; p++)
            *(uint4*)&Bs[(p * 16 + sr) * LDK + sc * 8] = breg[p];
        if (jt < 31) {                            // prefetch next tile (hidden by GEMM)
            const int j0n = jbase + (jt + 1) * 64;
#pragma unroll
            for (int p = 0; p < 4; p++)
                breg[p] = *(const uint4*)&Bt[((size_t)(j0n + p * 16 + sr)) * PCH + sc * 8];
        }
        __syncthreads();
        bf16x8 bfr[4];
#pragma unroll
        for (int s = 0; s < 4; s++)
            bfr[s] = *(bf16x8*)&Bs[(w * 16 + tx) * LDK + s * 32 + q * 8];
#pragma unroll
        for (int mt = 0; mt < 4; mt++) {
            floatx4 sacc = {0.f, 0.f, 0.f, 0.f};
#pragma unroll
            for (int s = 0; s < 4; s++)
                sacc = __builtin_amdgcn_mfma_f32_16x16x32_bf16(af[mt][s], bfr[s], sacc, 0, 0, 0);
#pragma unroll
            for (int r = 0; r < 4; r++)
                racc[mt][r] += __expf(sacc[r] * SCALEF);
        }
    }
    // reduce the 16 j-lanes, then atomicAdd partial row sums
#pragma unroll
    for (int mt = 0; mt < 4; mt++)
#pragma unroll
        for (int r = 0; r < 4; r++) {
            float v = racc[mt][r];
            v += __shfl_xor(v, 1); v += __shfl_xor(v, 2);
            v += __shfl_xor(v, 4); v += __shfl_xor(v, 8);
            if (tx == 0) atomicAdd(&zout[i0 + mt * 16 + q * 4 + r], v);
        }
}

// ---------------------------------------------------------------------------
// K3: attn — fus[i][d] += sum_{j in half} exp(scale*A_i.B_j)/zsum[j] * A_j[d]
// blockIdx.z = mode*2 + jsplit. 2 blocks/CU, B-tile reg prefetch, atomic out.
// ---------------------------------------------------------------------------
__global__ __launch_bounds__(256, 2) void attn_mfma(const bf16_t* __restrict__ pfT,
                                                    const bf16_t* __restrict__ riT,
                                                    const bf16_t* __restrict__ pfC,
                                                    const bf16_t* __restrict__ riC,
                                                    const float* __restrict__ zrsum,
                                                    const float* __restrict__ zcsum,
                                                    float* __restrict__ fus)
{
    __shared__ bf16_t As[64 * LDK];
    __shared__ bf16_t Bs[64 * LDK];
    __shared__ bf16_t Es[64 * LDJ];
    const int b = blockIdx.y, t = threadIdx.x;
    const int mode = blockIdx.z >> 1, js = blockIdx.z & 1;
    const bf16_t* At = (mode == 0 ? pfT : riT) + (size_t)b * NTOK * PCH;
    const bf16_t* Bt = (mode == 0 ? riT : pfT) + (size_t)b * NTOK * PCH;
    const bf16_t* Vc = (mode == 0 ? pfC : riC) + (size_t)b * PCH * NTOK;
    const float* wsum = (mode == 0 ? zcsum : zrsum) + (size_t)b * NTOK;
    const int lane = t & 63, w = t >> 6, tx = lane & 15, q = lane >> 4;
    const int i0 = blockIdx.x * 64;
    const int jbase = js * 2048;
    const int sr = t >> 4, sc = t & 15;

#pragma unroll
    for (int p = 0; p < 4; p++) {
        int i = p * 16 + sr;
        *(uint4*)&As[i * LDK + sc * 8] = *(const uint4*)&At[((size_t)(i0 + i)) * PCH + sc * 8];
    }
    __syncthreads();
    bf16x8 af[4][4];
#pragma unroll
    for (int mt = 0; mt < 4; mt++)
#pragma unroll
        for (int s = 0; s < 4; s++)
            af[mt][s] = *(bf16x8*)&As[(mt * 16 + tx) * LDK + s * 32 + q * 8];

    uint4 breg[4];
#pragma unroll
    for (int p = 0; p < 4; p++)
        breg[p] = *(const uint4*)&Bt[((size_t)(jbase + p * 16 + sr)) * PCH + sc * 8];

    floatx4 outacc[4][2];
#pragma unroll
    for (int mt = 0; mt < 4; mt++)
#pragma unroll
        for (int nt = 0; nt < 2; nt++)
            outacc[mt][nt] = (floatx4){0.f, 0.f, 0.f, 0.f};

    for (int jt = 0; jt < 32; jt++) {
        const int j0 = jbase + jt * 64;
        __syncthreads();                          // Bs + Es readers done
#pragma unroll
        for (int p = 0; p < 4; p++)
            *(uint4*)&Bs[(p * 16 + sr) * LDK + sc * 8] = breg[p];
        if (jt < 31) {
            const int j0n = j0 + 64;
#pragma unroll
            for (int p = 0; p < 4; p++)
                breg[p] = *(const uint4*)&Bt[((size_t)(j0n + p * 16 + sr)) * PCH + sc * 8];
        }
        __syncthreads();

        // ---- GEMM1 (wave's 16-j slice), exp * 1/zsum -> Es
        bf16x8 bfr[4];
#pragma unroll
        for (int s = 0; s < 4; s++)
            bfr[s] = *(bf16x8*)&Bs[(w * 16 + tx) * LDK + s * 32 + q * 8];
        const float wr = 1.0f / wsum[j0 + w * 16 + tx];
#pragma unroll
        for (int mt = 0; mt < 4; mt++) {
            floatx4 sacc = {0.f, 0.f, 0.f, 0.f};
#pragma unroll
            for (int s = 0; s < 4; s++)
                sacc = __builtin_amdgcn_mfma_f32_16x16x32_bf16(af[mt][s], bfr[s], sacc, 0, 0, 0);
#pragma unroll
            for (int r = 0; r < 4; r++) {
                float e = __expf(sacc[r] * SCALEF) * wr;
                Es[(mt * 16 + q * 4 + r) * LDJ + w * 16 + tx] = (bf16_t)e;
            }
        }
        __syncthreads();

        // ---- GEMM2: wave's 32-d slice, K = 64
        bf16x8 ef[4][2];
#pragma unroll
        for (int mt = 0; mt < 4; mt++)
#pragma unroll
            for (int s = 0; s < 2; s++)
                ef[mt][s] = *(bf16x8*)&Es[(mt * 16 + tx) * LDJ + s * 32 + q * 8];
#pragma unroll
        for (int nt = 0; nt < 2; nt++)
#pragma unroll
            for (int s = 0; s < 2; s++) {
                bf16x8 vf = *(const bf16x8*)&Vc[((size_t)(w * 32 + nt * 16 + tx)) * NTOK + j0 + s * 32 + q * 8];
#pragma unroll
                for (int mt = 0; mt < 4; mt++)
                    outacc[mt][nt] = __builtin_amdgcn_mfma_f32_16x16x32_bf16(ef[mt][s], vf, outacc[mt][nt], 0, 0, 0);
            }
    }

    // ---- epilogue: accumulate j-half partial into fus
    float* fo = fus + ((size_t)(b * NTOK + i0)) * 256 + mode * 128 + w * 32;
#pragma unroll
    for (int mt = 0; mt < 4; mt++)
#pragma unroll
        for (int nt = 0; nt < 2; nt++)
#pragma unroll
            for (int r = 0; r < 4; r++)
                atomicAdd(&fo[(mt * 16 + q * 4 + r) * 256 + nt * 16 + tx], outacc[mt][nt][r]);
}

// ---------------------------------------------------------------------------
// K4: 1x1 conv (256 -> 128) + BN(eval) + ReLU.
// ---------------------------------------------------------------------------
__global__ __launch_bounds__(256) void conv_kernel(const float* __restrict__ fus,
                                                   const float* __restrict__ cw,
                                                   const float* __restrict__ cb,
                                                   const float* __restrict__ g,
                                                   const float* __restrict__ be,
                                                   const float* __restrict__ mu,
                                                   const float* __restrict__ var,
                                                   float* __restrict__ out)
{
    __shared__ float Ls[64][260];   // 66.6 KB
    const int b = blockIdx.z, t = threadIdx.x;
    const int n0 = blockIdx.x * 64;
    const int obase = blockIdx.y * 32 + (t >> 6) * 8;   // wave-uniform

    const float4* src = (const float4*)(fus + ((size_t)(b * NTOK + n0)) * 256);
#pragma unroll
    for (int it = 0; it < 16; it++) {
        int row = it * 4 + (t >> 6);
        float4 v = src[row * 64 + (t & 63)];
        *(float4*)&Ls[row][(t & 63) * 4] = v;
    }
    __syncthreads();

    const int n = t & 63;
    float acc[8] = {};
    for (int c = 0; c < 256; c += 4) {
        float4 v = *(const float4*)&Ls[n][c];
#pragma unroll
        for (int oo = 0; oo < 8; oo++) {
            float4 wv = *(const float4*)&cw[(obase + oo) * 256 + c];
            acc[oo] += wv.x * v.x + wv.y * v.y + wv.z * v.z + wv.w * v.w;
        }
    }
#pragma unroll
    for (int oo = 0; oo < 8; oo++) {
        const int o = obase + oo;
        const float s  = g[o] * rsqrtf(var[o] + 1e-5f);
        const float b0 = be[o] + (cb[o] - mu[o]) * s;
        float y = acc[oo] * s + b0;
        out[((size_t)(b * OCH + o)) * NTOK + n0 + n] = fmaxf(y, 0.f);
    }
}

// ---------------------------------------------------------------------------
extern "C" void kernel_launch(void* const* d_in, const int* in_sizes, int n_in,
                              void* d_out, int out_size, void* d_ws, size_t ws_size,
                              hipStream_t stream)
{
    const float* pf   = (const float*)d_in[0];
    const float* img  = (const float*)d_in[1];
    const float* fc2w = (const float*)d_in[2];
    const float* fc2b = (const float*)d_in[3];
    const float* cw   = (const float*)d_in[4];
    const float* cb   = (const float*)d_in[5];
    const float* g    = (const float*)d_in[6];
    const float* be   = (const float*)d_in[7];
    const float* mu   = (const float*)d_in[8];
    const float* var  = (const float*)d_in[9];
    float* out = (float*)d_out;

    // ws layout: zeroed region FIRST (fus + zsums, contiguous), then packs.
    float* fus   = (float*)d_ws;                              // 8 MB
    float* zrsum = fus + (size_t)NB * NTOK * 256;             // 32 KB
    float* zcsum = zrsum + NB * NTOK;                         // 32 KB
    bf16_t* pfC = (bf16_t*)(zcsum + NB * NTOK);               // 2 MB
    bf16_t* pfT = pfC + (size_t)NB * PCH * NTOK;              // 2 MB
    bf16_t* riC = pfT + (size_t)NB * NTOK * PCH;              // 2 MB
    bf16_t* riT = riC + (size_t)NB * PCH * NTOK;              // 2 MB

    // zero fus + zsums: (2*4096*256 + 2*2*4096) floats = 528384 float4
    zero_kernel<<<dim3(2064), 256, 0, stream>>>((float4*)d_ws);
    pack_pf    <<<dim3(64, 2, NB),  256, 0, stream>>>(pf, pfC, pfT);
    fc2_kernel <<<dim3(64, 4, NB),  256, 0, stream>>>(img, fc2w, fc2b, riC, riT);
    stats_mfma <<<dim3(64, NB, 4),  256, 0, stream>>>(pfT, riT, zrsum, zcsum);
    attn_mfma  <<<dim3(64, NB, 4),  256, 0, stream>>>(pfT, riT, pfC, riC, zrsum, zcsum, fus);
    conv_kernel<<<dim3(64, 4, NB),  256, 0, stream>>>(fus, cw, cb, g, be, mu, var, out);
}

// Round 6
// 314.463 us; speedup vs baseline: 4.7007x; 1.1758x over previous
//
#include <hip/hip_runtime.h>
#include <math.h>

// Problem constants
#define NTOK 4096
#define PCH  128
#define ICH  256
#define OCH  128
#define NB   2
#define SCALEF 0.08838834764831845f   // 1/sqrt(128)

typedef __bf16 bf16_t;
typedef __attribute__((ext_vector_type(8))) __bf16 bf16x8;
typedef __attribute__((ext_vector_type(4))) __bf16 bf16x4;
typedef __attribute__((ext_vector_type(4))) float floatx4;

#define LDK 136   // padded row length (bf16 elems) for k=128 tiles
#define LDJ 72    // padded row length for j=64 tiles

// ---------------------------------------------------------------------------
// K-1: zero fus (8 MB) + zsum buffers (64 KB) — contiguous at ws start.
// 2064 blocks x 256 threads x float4 = 2,113,536 floats exactly.
// ---------------------------------------------------------------------------
__global__ __launch_bounds__(256) void zero_kernel(float4* __restrict__ p)
{
    p[(size_t)blockIdx.x * 256 + threadIdx.x] = float4{0.f, 0.f, 0.f, 0.f};
}

// ---------------------------------------------------------------------------
// K0: pack pf -> pfC (bf16 channel-major) + pfT (bf16 token-major)
// ---------------------------------------------------------------------------
__global__ __launch_bounds__(256) void pack_pf(const float* __restrict__ pf,
                                               bf16_t* __restrict__ pfC,
                                               bf16_t* __restrict__ pfT)
{
    __shared__ float Ls[64][65];
    const int t = threadIdx.x;
    const int n0 = blockIdx.x * 64, d0 = blockIdx.y * 64, b = blockIdx.z;
    const float* src = pf + ((size_t)(b * PCH + d0)) * NTOK + n0;
#pragma unroll
    for (int p = 0; p < 4; p++) {
        int d = p * 16 + (t >> 4), c = t & 15;
        float4 v = *(const float4*)&src[d * NTOK + c * 4];
        Ls[d][c * 4 + 0] = v.x; Ls[d][c * 4 + 1] = v.y;
        Ls[d][c * 4 + 2] = v.z; Ls[d][c * 4 + 3] = v.w;
        bf16x4 o = { (bf16_t)v.x, (bf16_t)v.y, (bf16_t)v.z, (bf16_t)v.w };
        *(bf16x4*)&pfC[((size_t)(b * PCH + d0 + d)) * NTOK + n0 + c * 4] = o;
    }
    __syncthreads();
#pragma unroll
    for (int p = 0; p < 2; p++) {
        int n = p * 32 + (t >> 3), c = t & 7;
        bf16x8 o;
#pragma unroll
        for (int k = 0; k < 8; k++) o[k] = (bf16_t)Ls[c * 8 + k][n];
        *(bf16x8*)&pfT[((size_t)(b * NTOK + n0 + n)) * PCH + d0 + c * 8] = o;
    }
}

// ---------------------------------------------------------------------------
// K1: fc2 — ri[b][p][n] = sum_c img[b][c][n]*w[p][c] + bias[p]
// ---------------------------------------------------------------------------
__global__ __launch_bounds__(256) void fc2_kernel(const float* __restrict__ img,
                                                  const float* __restrict__ w,
                                                  const float* __restrict__ bias,
                                                  bf16_t* __restrict__ riC,
                                                  bf16_t* __restrict__ riT)
{
    const int b = blockIdx.z, t = threadIdx.x;
    const int n = blockIdx.x * 64 + (t & 63);
    const int pbase = blockIdx.y * 32 + (t >> 6) * 8;   // wave-uniform
    const float* imgb = img + (size_t)b * ICH * NTOK + n;

    float acc[8];
#pragma unroll
    for (int pp = 0; pp < 8; pp++) acc[pp] = bias[pbase + pp];

    for (int c = 0; c < ICH; c += 4) {
        float v0 = imgb[(c + 0) * NTOK];
        float v1 = imgb[(c + 1) * NTOK];
        float v2 = imgb[(c + 2) * NTOK];
        float v3 = imgb[(c + 3) * NTOK];
#pragma unroll
        for (int pp = 0; pp < 8; pp++) {
            float4 wv = *(const float4*)&w[(pbase + pp) * ICH + c];
            acc[pp] += wv.x * v0 + wv.y * v1 + wv.z * v2 + wv.w * v3;
        }
    }

#pragma unroll
    for (int pp = 0; pp < 8; pp++)
        riC[((size_t)(b * PCH + pbase + pp)) * NTOK + n] = (bf16_t)acc[pp];
    bf16x8 tv;
#pragma unroll
    for (int pp = 0; pp < 8; pp++) tv[pp] = (bf16_t)acc[pp];
    *(bf16x8*)&riT[((size_t)(b * NTOK + n)) * PCH + pbase] = tv;
}

// ---------------------------------------------------------------------------
// K2: stats — zsum[i] += sum_{j in half} exp(scale * A_i . B_j)  (atomicAdd)
// R4 semantics; NEW: double-buffered Bs -> ONE barrier per j-tile.
// ---------------------------------------------------------------------------
__global__ __launch_bounds__(256, 2) void stats_mfma(const bf16_t* __restrict__ pfT,
                                                     const bf16_t* __restrict__ riT,
                                                     float* __restrict__ zr,
                                                     float* __restrict__ zc)
{
    __shared__ bf16_t As[64 * LDK];
    __shared__ bf16_t Bs[2][64 * LDK];
    const int b = blockIdx.y, t = threadIdx.x;
    const int mode = blockIdx.z >> 1, js = blockIdx.z & 1;
    const bf16_t* At = (mode == 0 ? pfT : riT) + (size_t)b * NTOK * PCH;
    const bf16_t* Bt = (mode == 0 ? riT : pfT) + (size_t)b * NTOK * PCH;
    float* zout = (mode == 0 ? zr : zc) + (size_t)b * NTOK;
    const int lane = t & 63, w = t >> 6, tx = lane & 15, q = lane >> 4;
    const int i0 = blockIdx.x * 64;
    const int jbase = js * 2048;
    const int sr = t >> 4, sc = t & 15;

    // first B tile into registers, then stage A band
    uint4 breg[4];
#pragma unroll
    for (int p = 0; p < 4; p++)
        breg[p] = *(const uint4*)&Bt[((size_t)(jbase + p * 16 + sr)) * PCH + sc * 8];
#pragma unroll
    for (int p = 0; p < 4; p++) {
        int i = p * 16 + sr;
        *(uint4*)&As[i * LDK + sc * 8] = *(const uint4*)&At[((size_t)(i0 + i)) * PCH + sc * 8];
    }
    __syncthreads();
    bf16x8 af[4][4];
#pragma unroll
    for (int mt = 0; mt < 4; mt++)
#pragma unroll
        for (int s = 0; s < 4; s++)
            af[mt][s] = *(bf16x8*)&As[(mt * 16 + tx) * LDK + s * 32 + q * 8];

    // stage Bs[0], prefetch tile 1
#pragma unroll
    for (int p = 0; p < 4; p++)
        *(uint4*)&Bs[0][(p * 16 + sr) * LDK + sc * 8] = breg[p];
#pragma unroll
    for (int p = 0; p < 4; p++)
        breg[p] = *(const uint4*)&Bt[((size_t)(jbase + 64 + p * 16 + sr)) * PCH + sc * 8];

    float racc[4][4] = {};
    for (int jt = 0; jt < 32; jt++) {
        const int cur = jt & 1;
        __syncthreads();                         // Bs[cur] visible; prev reads drained
        bf16x8 bfr[4];
#pragma unroll
        for (int s = 0; s < 4; s++)
            bfr[s] = *(bf16x8*)&Bs[cur][(w * 16 + tx) * LDK + s * 32 + q * 8];
        if (jt < 31) {                           // stage next buf while cur is read
#pragma unroll
            for (int p = 0; p < 4; p++)
                *(uint4*)&Bs[cur ^ 1][(p * 16 + sr) * LDK + sc * 8] = breg[p];
            if (jt < 30) {
                const int j0n = jbase + (jt + 2) * 64;
#pragma unroll
                for (int p = 0; p < 4; p++)
                    breg[p] = *(const uint4*)&Bt[((size_t)(j0n + p * 16 + sr)) * PCH + sc * 8];
            }
        }
#pragma unroll
        for (int mt = 0; mt < 4; mt++) {
            floatx4 sacc = {0.f, 0.f, 0.f, 0.f};
#pragma unroll
            for (int s = 0; s < 4; s++)
                sacc = __builtin_amdgcn_mfma_f32_16x16x32_bf16(af[mt][s], bfr[s], sacc, 0, 0, 0);
#pragma unroll
            for (int r = 0; r < 4; r++)
                racc[mt][r] += __expf(sacc[r] * SCALEF);
        }
    }
#pragma unroll
    for (int mt = 0; mt < 4; mt++)
#pragma unroll
        for (int r = 0; r < 4; r++) {
            float v = racc[mt][r];
            v += __shfl_xor(v, 1); v += __shfl_xor(v, 2);
            v += __shfl_xor(v, 4); v += __shfl_xor(v, 8);
            if (tx == 0) atomicAdd(&zout[i0 + mt * 16 + q * 4 + r], v);
        }
}

// ---------------------------------------------------------------------------
// K3: attn — fus[i][d] += sum_{j in half} exp(scale*A_i.B_j)/zsum[j] * A_j[d]
// R4 semantics (E scaled by 1/zsum). NEW: dbuf Bs + V-frag + wsum prefetch.
// ---------------------------------------------------------------------------
__global__ __launch_bounds__(256, 2) void attn_mfma(const bf16_t* __restrict__ pfT,
                                                    const bf16_t* __restrict__ riT,
                                                    const bf16_t* __restrict__ pfC,
                                                    const bf16_t* __restrict__ riC,
                                                    const float* __restrict__ zrsum,
                                                    const float* __restrict__ zcsum,
                                                    float* __restrict__ fus)
{
    __shared__ bf16_t As[64 * LDK];
    __shared__ bf16_t Bs[2][64 * LDK];
    __shared__ bf16_t Es[64 * LDJ];
    const int b = blockIdx.y, t = threadIdx.x;
    const int mode = blockIdx.z >> 1, js = blockIdx.z & 1;
    const bf16_t* At = (mode == 0 ? pfT : riT) + (size_t)b * NTOK * PCH;
    const bf16_t* Bt = (mode == 0 ? riT : pfT) + (size_t)b * NTOK * PCH;
    const bf16_t* Vc = (mode == 0 ? pfC : riC) + (size_t)b * PCH * NTOK;
    const float* wsum = (mode == 0 ? zcsum : zrsum) + (size_t)b * NTOK;
    const int lane = t & 63, w = t >> 6, tx = lane & 15, q = lane >> 4;
    const int i0 = blockIdx.x * 64;
    const int jbase = js * 2048;
    const int sr = t >> 4, sc = t & 15;

    // first B tile + first V tile + first wsum into registers
    uint4 breg[4];
#pragma unroll
    for (int p = 0; p < 4; p++)
        breg[p] = *(const uint4*)&Bt[((size_t)(jbase + p * 16 + sr)) * PCH + sc * 8];
    bf16x8 vcur[2][2];
#pragma unroll
    for (int nt = 0; nt < 2; nt++)
#pragma unroll
        for (int s = 0; s < 2; s++)
            vcur[nt][s] = *(const bf16x8*)&Vc[((size_t)(w * 32 + nt * 16 + tx)) * NTOK + jbase + s * 32 + q * 8];
    float wrcur = 1.0f / wsum[jbase + w * 16 + tx];

#pragma unroll
    for (int p = 0; p < 4; p++) {
        int i = p * 16 + sr;
        *(uint4*)&As[i * LDK + sc * 8] = *(const uint4*)&At[((size_t)(i0 + i)) * PCH + sc * 8];
    }
    __syncthreads();
    bf16x8 af[4][4];
#pragma unroll
    for (int mt = 0; mt < 4; mt++)
#pragma unroll
        for (int s = 0; s < 4; s++)
            af[mt][s] = *(bf16x8*)&As[(mt * 16 + tx) * LDK + s * 32 + q * 8];

    // stage Bs[0], prefetch tile 1
#pragma unroll
    for (int p = 0; p < 4; p++)
        *(uint4*)&Bs[0][(p * 16 + sr) * LDK + sc * 8] = breg[p];
#pragma unroll
    for (int p = 0; p < 4; p++)
        breg[p] = *(const uint4*)&Bt[((size_t)(jbase + 64 + p * 16 + sr)) * PCH + sc * 8];

    floatx4 outacc[4][2];
#pragma unroll
    for (int mt = 0; mt < 4; mt++)
#pragma unroll
        for (int nt = 0; nt < 2; nt++)
            outacc[mt][nt] = (floatx4){0.f, 0.f, 0.f, 0.f};

    for (int jt = 0; jt < 32; jt++) {
        const int cur = jt & 1;
        const int j0 = jbase + jt * 64;
        __syncthreads();                         // SYNC_top: Bs[cur] ready, Es free

        bf16x8 bfr[4];
#pragma unroll
        for (int s = 0; s < 4; s++)
            bfr[s] = *(bf16x8*)&Bs[cur][(w * 16 + tx) * LDK + s * 32 + q * 8];

        // prefetch next V tile + next wsum (land during GEMM1+exp)
        bf16x8 vnext[2][2];
        float wnext = 0.f;
        if (jt < 31) {
            wnext = wsum[j0 + 64 + w * 16 + tx];
#pragma unroll
            for (int nt = 0; nt < 2; nt++)
#pragma unroll
                for (int s = 0; s < 2; s++)
                    vnext[nt][s] = *(const bf16x8*)&Vc[((size_t)(w * 32 + nt * 16 + tx)) * NTOK + (j0 + 64) + s * 32 + q * 8];
        }

        // ---- GEMM1 (wave's 16-j slice), exp * 1/zsum -> Es
#pragma unroll
        for (int mt = 0; mt < 4; mt++) {
            floatx4 sacc = {0.f, 0.f, 0.f, 0.f};
#pragma unroll
            for (int s = 0; s < 4; s++)
                sacc = __builtin_amdgcn_mfma_f32_16x16x32_bf16(af[mt][s], bfr[s], sacc, 0, 0, 0);
#pragma unroll
            for (int r = 0; r < 4; r++) {
                float e = __expf(sacc[r] * SCALEF) * wrcur;
                Es[(mt * 16 + q * 4 + r) * LDJ + w * 16 + tx] = (bf16_t)e;
            }
        }

        // stage next B buffer while current is being read elsewhere
        if (jt < 31) {
#pragma unroll
            for (int p = 0; p < 4; p++)
                *(uint4*)&Bs[cur ^ 1][(p * 16 + sr) * LDK + sc * 8] = breg[p];
            if (jt < 30) {
                const int j0n = j0 + 128;
#pragma unroll
                for (int p = 0; p < 4; p++)
                    breg[p] = *(const uint4*)&Bt[((size_t)(j0n + p * 16 + sr)) * PCH + sc * 8];
            }
        }
        __syncthreads();                         // SYNC_mid: Es + Bs[nxt] visible

        // ---- GEMM2: wave's 32-d slice, K = 64
        bf16x8 ef[4][2];
#pragma unroll
        for (int mt = 0; mt < 4; mt++)
#pragma unroll
            for (int s = 0; s < 2; s++)
                ef[mt][s] = *(bf16x8*)&Es[(mt * 16 + tx) * LDJ + s * 32 + q * 8];
#pragma unroll
        for (int nt = 0; nt < 2; nt++)
#pragma unroll
            for (int s = 0; s < 2; s++)
#pragma unroll
                for (int mt = 0; mt < 4; mt++)
                    outacc[mt][nt] = __builtin_amdgcn_mfma_f32_16x16x32_bf16(ef[mt][s], vcur[nt][s], outacc[mt][nt], 0, 0, 0);

        if (jt < 31) {
            wrcur = 1.0f / wnext;                // off the GEMM1->Es critical path
#pragma unroll
            for (int nt = 0; nt < 2; nt++)
#pragma unroll
                for (int s = 0; s < 2; s++)
                    vcur[nt][s] = vnext[nt][s];
        }
    }

    // ---- epilogue: accumulate j-half partial into fus
    float* fo = fus + ((size_t)(b * NTOK + i0)) * 256 + mode * 128 + w * 32;
#pragma unroll
    for (int mt = 0; mt < 4; mt++)
#pragma unroll
        for (int nt = 0; nt < 2; nt++)
#pragma unroll
            for (int r = 0; r < 4; r++)
                atomicAdd(&fo[(mt * 16 + q * 4 + r) * 256 + nt * 16 + tx], outacc[mt][nt][r]);
}

// ---------------------------------------------------------------------------
// K4: 1x1 conv (256 -> 128) + BN(eval) + ReLU.
// ---------------------------------------------------------------------------
__global__ __launch_bounds__(256) void conv_kernel(const float* __restrict__ fus,
                                                   const float* __restrict__ cw,
                                                   const float* __restrict__ cb,
                                                   const float* __restrict__ g,
                                                   const float* __restrict__ be,
                                                   const float* __restrict__ mu,
                                                   const float* __restrict__ var,
                                                   float* __restrict__ out)
{
    __shared__ float Ls[64][260];
    const int b = blockIdx.z, t = threadIdx.x;
    const int n0 = blockIdx.x * 64;
    const int obase = blockIdx.y * 32 + (t >> 6) * 8;   // wave-uniform

    const float4* src = (const float4*)(fus + ((size_t)(b * NTOK + n0)) * 256);
#pragma unroll
    for (int it = 0; it < 16; it++) {
        int row = it * 4 + (t >> 6);
        float4 v = src[row * 64 + (t & 63)];
        *(float4*)&Ls[row][(t & 63) * 4] = v;
    }
    __syncthreads();

    const int n = t & 63;
    float acc[8] = {};
    for (int c = 0; c < 256; c += 4) {
        float4 v = *(const float4*)&Ls[n][c];
#pragma unroll
        for (int oo = 0; oo < 8; oo++) {
            float4 wv = *(const float4*)&cw[(obase + oo) * 256 + c];
            acc[oo] += wv.x * v.x + wv.y * v.y + wv.z * v.z + wv.w * v.w;
        }
    }
#pragma unroll
    for (int oo = 0; oo < 8; oo++) {
        const int o = obase + oo;
        const float s  = g[o] * rsqrtf(var[o] + 1e-5f);
        const float b0 = be[o] + (cb[o] - mu[o]) * s;
        float y = acc[oo] * s + b0;
        out[((size_t)(b * OCH + o)) * NTOK + n0 + n] = fmaxf(y, 0.f);
    }
}

// ---------------------------------------------------------------------------
extern "C" void kernel_launch(void* const* d_in, const int* in_sizes, int n_in,
                              void* d_out, int out_size, void* d_ws, size_t ws_size,
                              hipStream_t stream)
{
    const float* pf   = (const float*)d_in[0];
    const float* img  = (const float*)d_in[1];
    const float* fc2w = (const float*)d_in[2];
    const float* fc2b = (const float*)d_in[3];
    const float* cw   = (const float*)d_in[4];
    const float* cb   = (const float*)d_in[5];
    const float* g    = (const float*)d_in[6];
    const float* be   = (const float*)d_in[7];
    const float* mu   = (const float*)d_in[8];
    const float* var  = (const float*)d_in[9];
    float* out = (float*)d_out;

    // ws layout: EXACTLY R4's proven footprint (16,842,752 B).
    float* fus   = (float*)d_ws;                              // 8 MB
    float* zrsum = fus + (size_t)NB * NTOK * 256;             // 32 KB
    float* zcsum = zrsum + NB * NTOK;                         // 32 KB
    bf16_t* pfC = (bf16_t*)(zcsum + NB * NTOK);               // 2 MB
    bf16_t* pfT = pfC + (size_t)NB * PCH * NTOK;              // 2 MB
    bf16_t* riC = pfT + (size_t)NB * NTOK * PCH;              // 2 MB
    bf16_t* riT = riC + (size_t)NB * PCH * NTOK;              // 2 MB

    // zero fus + zsums: (2*4096*256 + 2*2*4096) floats = 528384 float4
    zero_kernel<<<dim3(2064), 256, 0, stream>>>((float4*)d_ws);
    pack_pf    <<<dim3(64, 2, NB),  256, 0, stream>>>(pf, pfC, pfT);
    fc2_kernel <<<dim3(64, 4, NB),  256, 0, stream>>>(img, fc2w, fc2b, riC, riT);
    stats_mfma <<<dim3(64, NB, 4),  256, 0, stream>>>(pfT, riT, zrsum, zcsum);
    attn_mfma  <<<dim3(64, NB, 4),  256, 0, stream>>>(pfT, riT, pfC, riC, zrsum, zcsum, fus);
    conv_kernel<<<dim3(64, 4, NB),  256, 0, stream>>>(fus, cw, cb, g, be, mu, var, out);
}

// Round 7
// 312.585 us; speedup vs baseline: 4.7289x; 1.0060x over previous
//
#include <hip/hip_runtime.h>
#include <math.h>

// Problem constants
#define NTOK 4096
#define PCH  128
#define ICH  256
#define OCH  128
#define NB   2
#define SCALEF 0.08838834764831845f   // 1/sqrt(128)

typedef __bf16 bf16_t;
typedef __attribute__((ext_vector_type(8))) __bf16 bf16x8;
typedef __attribute__((ext_vector_type(4))) __bf16 bf16x4;
typedef __attribute__((ext_vector_type(4))) float floatx4;

#define LDK 136   // padded row length (bf16 elems) for k=128 tiles
#define LDJ 72    // padded row length for j=64 tiles

// ---------------------------------------------------------------------------
// K-1: zero fus (8 MB) + zsum buffers (64 KB) — contiguous at ws start.
// 2064 blocks x 256 threads x float4 = 2,113,536 floats exactly.
// ---------------------------------------------------------------------------
__global__ __launch_bounds__(256) void zero_kernel(float4* __restrict__ p)
{
    p[(size_t)blockIdx.x * 256 + threadIdx.x] = float4{0.f, 0.f, 0.f, 0.f};
}

// ---------------------------------------------------------------------------
// K0: pack pf -> pfC (bf16 channel-major) + pfT (bf16 token-major)
// ---------------------------------------------------------------------------
__global__ __launch_bounds__(256) void pack_pf(const float* __restrict__ pf,
                                               bf16_t* __restrict__ pfC,
                                               bf16_t* __restrict__ pfT)
{
    __shared__ float Ls[64][65];
    const int t = threadIdx.x;
    const int n0 = blockIdx.x * 64, d0 = blockIdx.y * 64, b = blockIdx.z;
    const float* src = pf + ((size_t)(b * PCH + d0)) * NTOK + n0;
#pragma unroll
    for (int p = 0; p < 4; p++) {
        int d = p * 16 + (t >> 4), c = t & 15;
        float4 v = *(const float4*)&src[d * NTOK + c * 4];
        Ls[d][c * 4 + 0] = v.x; Ls[d][c * 4 + 1] = v.y;
        Ls[d][c * 4 + 2] = v.z; Ls[d][c * 4 + 3] = v.w;
        bf16x4 o = { (bf16_t)v.x, (bf16_t)v.y, (bf16_t)v.z, (bf16_t)v.w };
        *(bf16x4*)&pfC[((size_t)(b * PCH + d0 + d)) * NTOK + n0 + c * 4] = o;
    }
    __syncthreads();
#pragma unroll
    for (int p = 0; p < 2; p++) {
        int n = p * 32 + (t >> 3), c = t & 7;
        bf16x8 o;
#pragma unroll
        for (int k = 0; k < 8; k++) o[k] = (bf16_t)Ls[c * 8 + k][n];
        *(bf16x8*)&pfT[((size_t)(b * NTOK + n0 + n)) * PCH + d0 + c * 8] = o;
    }
}

// ---------------------------------------------------------------------------
// K1: fc2 — ri[b][p][n] = sum_c img[b][c][n]*w[p][c] + bias[p]
// ---------------------------------------------------------------------------
__global__ __launch_bounds__(256) void fc2_kernel(const float* __restrict__ img,
                                                  const float* __restrict__ w,
                                                  const float* __restrict__ bias,
                                                  bf16_t* __restrict__ riC,
                                                  bf16_t* __restrict__ riT)
{
    const int b = blockIdx.z, t = threadIdx.x;
    const int n = blockIdx.x * 64 + (t & 63);
    const int pbase = blockIdx.y * 32 + (t >> 6) * 8;   // wave-uniform
    const float* imgb = img + (size_t)b * ICH * NTOK + n;

    float acc[8];
#pragma unroll
    for (int pp = 0; pp < 8; pp++) acc[pp] = bias[pbase + pp];

    for (int c = 0; c < ICH; c += 4) {
        float v0 = imgb[(c + 0) * NTOK];
        float v1 = imgb[(c + 1) * NTOK];
        float v2 = imgb[(c + 2) * NTOK];
        float v3 = imgb[(c + 3) * NTOK];
#pragma unroll
        for (int pp = 0; pp < 8; pp++) {
            float4 wv = *(const float4*)&w[(pbase + pp) * ICH + c];
            acc[pp] += wv.x * v0 + wv.y * v1 + wv.z * v2 + wv.w * v3;
        }
    }

#pragma unroll
    for (int pp = 0; pp < 8; pp++)
        riC[((size_t)(b * PCH + pbase + pp)) * NTOK + n] = (bf16_t)acc[pp];
    bf16x8 tv;
#pragma unroll
    for (int pp = 0; pp < 8; pp++) tv[pp] = (bf16_t)acc[pp];
    *(bf16x8*)&riT[((size_t)(b * NTOK + n)) * PCH + pbase] = tv;
}

// ---------------------------------------------------------------------------
// K2: stats — zsum[i] += sum_{j in quarter} exp(scale * A_i . B_j) (atomicAdd)
// v3: NO Bs staging (each wave reads a private 16-j slice -> direct global
// with 1-tile prefetch), swapped GEMM (S^T tile), BARRIER-FREE main loop.
// blockIdx.z = mode*4 + js (j quarter). Grid 1024 -> 4 blocks/CU.
// ---------------------------------------------------------------------------
__global__ __launch_bounds__(256, 4) void stats_mfma(const bf16_t* __restrict__ pfT,
                                                     const bf16_t* __restrict__ riT,
                                                     float* __restrict__ zr,
                                                     float* __restrict__ zc)
{
    __shared__ bf16_t As[64 * LDK];
    const int b = blockIdx.y, t = threadIdx.x;
    const int mode = blockIdx.z >> 2, js = blockIdx.z & 3;
    const bf16_t* At = (mode == 0 ? pfT : riT) + (size_t)b * NTOK * PCH;
    const bf16_t* Bt = (mode == 0 ? riT : pfT) + (size_t)b * NTOK * PCH;
    float* zout = (mode == 0 ? zr : zc) + (size_t)b * NTOK;
    const int lane = t & 63, w = t >> 6, tx = lane & 15, q = lane >> 4;
    const int i0 = blockIdx.x * 64;
    const int jbase = js * 1024;
    const int sr = t >> 4, sc = t & 15;
    const bf16_t* Brow = Bt + (size_t)(jbase + w * 16 + tx) * PCH;  // this lane's j-row base

    // prefetch first B fragments (jt=0), then stage A band
    bf16x8 bcur[4];
#pragma unroll
    for (int s = 0; s < 4; s++)
        bcur[s] = *(const bf16x8*)&Brow[s * 32 + q * 8];
#pragma unroll
    for (int p = 0; p < 4; p++) {
        int i = p * 16 + sr;
        *(uint4*)&As[i * LDK + sc * 8] = *(const uint4*)&At[((size_t)(i0 + i)) * PCH + sc * 8];
    }
    __syncthreads();
    bf16x8 af[4][4];
#pragma unroll
    for (int mt = 0; mt < 4; mt++)
#pragma unroll
        for (int s = 0; s < 4; s++)
            af[mt][s] = *(bf16x8*)&As[(mt * 16 + tx) * LDK + s * 32 + q * 8];

    float racc[4] = {0.f, 0.f, 0.f, 0.f};
    for (int jt = 0; jt < 16; jt++) {
        // swapped GEMM1: D[m=j_local][n=i_local]; lane holds j=jbase+jt*64+w*16+q*4+r,
        // i = i0+mt*16+tx
        floatx4 sacc[4];
#pragma unroll
        for (int mt = 0; mt < 4; mt++) {
            sacc[mt] = (floatx4){0.f, 0.f, 0.f, 0.f};
#pragma unroll
            for (int s = 0; s < 4; s++)
                sacc[mt] = __builtin_amdgcn_mfma_f32_16x16x32_bf16(bcur[s], af[mt][s], sacc[mt], 0, 0, 0);
        }
        if (jt < 15) {                            // reload B for next tile (latency
            const bf16_t* bn = Brow + (size_t)(jt + 1) * 64 * PCH;   // hidden by exp)
#pragma unroll
            for (int s = 0; s < 4; s++)
                bcur[s] = *(const bf16x8*)&bn[s * 32 + q * 8];
        }
#pragma unroll
        for (int mt = 0; mt < 4; mt++)
#pragma unroll
            for (int r = 0; r < 4; r++)
                racc[mt] += __expf(sacc[mt][r] * SCALEF);
    }
    // racc[mt] = partial sum over this (w,q) j-stripe for i = i0+mt*16+tx.
    // Combine quads (xor 16, 32), then one atomicAdd per i from q==0 lanes.
#pragma unroll
    for (int mt = 0; mt < 4; mt++) {
        float v = racc[mt];
        v += __shfl_xor(v, 16);
        v += __shfl_xor(v, 32);
        if (q == 0) atomicAdd(&zout[i0 + mt * 16 + tx], v);
    }
}

// ---------------------------------------------------------------------------
// K3: attn — fus[i][d] += sum_{j in quarter} exp(scale*A_i.B_j)/zsum[j]*A_j[d]
// v3: no Bs staging (direct global B-frag prefetch), swapped GEMM1 -> Es
// written with b64 (4 consecutive j at fixed i), Es double-buffered -> ONE
// barrier per j-tile. V-frag + wsum(float4) prefetch. Grid 1024, 3 blocks/CU.
// ---------------------------------------------------------------------------
__global__ __launch_bounds__(256, 3) void attn_mfma(const bf16_t* __restrict__ pfT,
                                                    const bf16_t* __restrict__ riT,
                                                    const bf16_t* __restrict__ pfC,
                                                    const bf16_t* __restrict__ riC,
                                                    const float* __restrict__ zrsum,
                                                    const float* __restrict__ zcsum,
                                                    float* __restrict__ fus)
{
    __shared__ bf16_t As[64 * LDK];
    __shared__ bf16_t Es[2][64 * LDJ];
    const int b = blockIdx.y, t = threadIdx.x;
    const int mode = blockIdx.z >> 2, js = blockIdx.z & 3;
    const bf16_t* At = (mode == 0 ? pfT : riT) + (size_t)b * NTOK * PCH;
    const bf16_t* Bt = (mode == 0 ? riT : pfT) + (size_t)b * NTOK * PCH;
    const bf16_t* Vc = (mode == 0 ? pfC : riC) + (size_t)b * PCH * NTOK;
    const float* wsum = (mode == 0 ? zcsum : zrsum) + (size_t)b * NTOK;
    const int lane = t & 63, w = t >> 6, tx = lane & 15, q = lane >> 4;
    const int i0 = blockIdx.x * 64;
    const int jbase = js * 1024;
    const int sr = t >> 4, sc = t & 15;
    const bf16_t* Brow = Bt + (size_t)(jbase + w * 16 + tx) * PCH;

    // prefetch B frags (jt=0), V frags (jt=0), wsum quad (jt=0)
    bf16x8 bcur[4];
#pragma unroll
    for (int s = 0; s < 4; s++)
        bcur[s] = *(const bf16x8*)&Brow[s * 32 + q * 8];
    bf16x8 vcur[2][2];
#pragma unroll
    for (int nt = 0; nt < 2; nt++)
#pragma unroll
        for (int s = 0; s < 2; s++)
            vcur[nt][s] = *(const bf16x8*)&Vc[((size_t)(w * 32 + nt * 16 + tx)) * NTOK + jbase + s * 32 + q * 8];
    float4 wv = *(const float4*)&wsum[jbase + w * 16 + q * 4];
    float4 wr4 = {1.f / wv.x, 1.f / wv.y, 1.f / wv.z, 1.f / wv.w};

#pragma unroll
    for (int p = 0; p < 4; p++) {
        int i = p * 16 + sr;
        *(uint4*)&As[i * LDK + sc * 8] = *(const uint4*)&At[((size_t)(i0 + i)) * PCH + sc * 8];
    }
    __syncthreads();
    bf16x8 af[4][4];
#pragma unroll
    for (int mt = 0; mt < 4; mt++)
#pragma unroll
        for (int s = 0; s < 4; s++)
            af[mt][s] = *(bf16x8*)&As[(mt * 16 + tx) * LDK + s * 32 + q * 8];

    floatx4 outacc[4][2];
#pragma unroll
    for (int mt = 0; mt < 4; mt++)
#pragma unroll
        for (int nt = 0; nt < 2; nt++)
            outacc[mt][nt] = (floatx4){0.f, 0.f, 0.f, 0.f};

    for (int jt = 0; jt < 16; jt++) {
        const int cur = jt & 1;
        const int j0 = jbase + jt * 64;

        // ---- GEMM1 (swapped): lane holds S^T: j = j0+w*16+q*4+r, i = i0+mt*16+tx
        floatx4 sacc[4];
#pragma unroll
        for (int mt = 0; mt < 4; mt++) {
            sacc[mt] = (floatx4){0.f, 0.f, 0.f, 0.f};
#pragma unroll
            for (int s = 0; s < 4; s++)
                sacc[mt] = __builtin_amdgcn_mfma_f32_16x16x32_bf16(bcur[s], af[mt][s], sacc[mt], 0, 0, 0);
        }
        if (jt < 15) {                            // reload B frags for next tile
            const bf16_t* bn = Brow + (size_t)(jt + 1) * 64 * PCH;
#pragma unroll
            for (int s = 0; s < 4; s++)
                bcur[s] = *(const bf16x8*)&bn[s * 32 + q * 8];
        }

        // ---- exp * 1/zsum -> Es[cur][i][j] (one b64 per mt: 4 consecutive j)
#pragma unroll
        for (int mt = 0; mt < 4; mt++) {
            bf16x4 ev;
#pragma unroll
            for (int r = 0; r < 4; r++)
                ev[r] = (bf16_t)(__expf(sacc[mt][r] * SCALEF) * ((const float*)&wr4)[r]);
            *(bf16x4*)&Es[cur][(mt * 16 + tx) * LDJ + w * 16 + q * 4] = ev;
        }
        float4 wnv;
        if (jt < 15)                              // prefetch next wsum quad
            wnv = *(const float4*)&wsum[j0 + 64 + w * 16 + q * 4];

        __syncthreads();                          // Es[cur] visible; prev readers done

        // ---- GEMM2: out[i][d], K = this 64-j tile
        bf16x8 ef[4][2];
#pragma unroll
        for (int mt = 0; mt < 4; mt++)
#pragma unroll
            for (int s = 0; s < 2; s++)
                ef[mt][s] = *(bf16x8*)&Es[cur][(mt * 16 + tx) * LDJ + s * 32 + q * 8];
#pragma unroll
        for (int nt = 0; nt < 2; nt++)
#pragma unroll
            for (int s = 0; s < 2; s++)
#pragma unroll
                for (int mt = 0; mt < 4; mt++)
                    outacc[mt][nt] = __builtin_amdgcn_mfma_f32_16x16x32_bf16(ef[mt][s], vcur[nt][s], outacc[mt][nt], 0, 0, 0);

        if (jt < 15) {                            // reload V frags + finish wsum rcp
#pragma unroll
            for (int nt = 0; nt < 2; nt++)
#pragma unroll
                for (int s = 0; s < 2; s++)
                    vcur[nt][s] = *(const bf16x8*)&Vc[((size_t)(w * 32 + nt * 16 + tx)) * NTOK + (j0 + 64) + s * 32 + q * 8];
            wr4 = (float4){1.f / wnv.x, 1.f / wnv.y, 1.f / wnv.z, 1.f / wnv.w};
        }
    }

    // ---- epilogue: accumulate j-quarter partial into fus
    float* fo = fus + ((size_t)(b * NTOK + i0)) * 256 + mode * 128 + w * 32;
#pragma unroll
    for (int mt = 0; mt < 4; mt++)
#pragma unroll
        for (int nt = 0; nt < 2; nt++)
#pragma unroll
            for (int r = 0; r < 4; r++)
                atomicAdd(&fo[(mt * 16 + q * 4 + r) * 256 + nt * 16 + tx], outacc[mt][nt][r]);
}

// ---------------------------------------------------------------------------
// K4: 1x1 conv (256 -> 128) + BN(eval) + ReLU.
// ---------------------------------------------------------------------------
__global__ __launch_bounds__(256) void conv_kernel(const float* __restrict__ fus,
                                                   const float* __restrict__ cw,
                                                   const float* __restrict__ cb,
                                                   const float* __restrict__ g,
                                                   const float* __restrict__ be,
                                                   const float* __restrict__ mu,
                                                   const float* __restrict__ var,
                                                   float* __restrict__ out)
{
    __shared__ float Ls[64][260];
    const int b = blockIdx.z, t = threadIdx.x;
    const int n0 = blockIdx.x * 64;
    const int obase = blockIdx.y * 32 + (t >> 6) * 8;   // wave-uniform

    const float4* src = (const float4*)(fus + ((size_t)(b * NTOK + n0)) * 256);
#pragma unroll
    for (int it = 0; it < 16; it++) {
        int row = it * 4 + (t >> 6);
        float4 v = src[row * 64 + (t & 63)];
        *(float4*)&Ls[row][(t & 63) * 4] = v;
    }
    __syncthreads();

    const int n = t & 63;
    float acc[8] = {};
    for (int c = 0; c < 256; c += 4) {
        float4 v = *(const float4*)&Ls[n][c];
#pragma unroll
        for (int oo = 0; oo < 8; oo++) {
            float4 wv = *(const float4*)&cw[(obase + oo) * 256 + c];
            acc[oo] += wv.x * v.x + wv.y * v.y + wv.z * v.z + wv.w * v.w;
        }
    }
#pragma unroll
    for (int oo = 0; oo < 8; oo++) {
        const int o = obase + oo;
        const float s  = g[o] * rsqrtf(var[o] + 1e-5f);
        const float b0 = be[o] + (cb[o] - mu[o]) * s;
        float y = acc[oo] * s + b0;
        out[((size_t)(b * OCH + o)) * NTOK + n0 + n] = fmaxf(y, 0.f);
    }
}

// ---------------------------------------------------------------------------
extern "C" void kernel_launch(void* const* d_in, const int* in_sizes, int n_in,
                              void* d_out, int out_size, void* d_ws, size_t ws_size,
                              hipStream_t stream)
{
    const float* pf   = (const float*)d_in[0];
    const float* img  = (const float*)d_in[1];
    const float* fc2w = (const float*)d_in[2];
    const float* fc2b = (const float*)d_in[3];
    const float* cw   = (const float*)d_in[4];
    const float* cb   = (const float*)d_in[5];
    const float* g    = (const float*)d_in[6];
    const float* be   = (const float*)d_in[7];
    const float* mu   = (const float*)d_in[8];
    const float* var  = (const float*)d_in[9];
    float* out = (float*)d_out;

    // ws layout: EXACTLY R4/R6's proven footprint (16,842,752 B).
    float* fus   = (float*)d_ws;                              // 8 MB
    float* zrsum = fus + (size_t)NB * NTOK * 256;             // 32 KB
    float* zcsum = zrsum + NB * NTOK;                         // 32 KB
    bf16_t* pfC = (bf16_t*)(zcsum + NB * NTOK);               // 2 MB
    bf16_t* pfT = pfC + (size_t)NB * PCH * NTOK;              // 2 MB
    bf16_t* riC = pfT + (size_t)NB * NTOK * PCH;              // 2 MB
    bf16_t* riT = riC + (size_t)NB * PCH * NTOK;              // 2 MB

    // zero fus + zsums: (2*4096*256 + 2*2*4096) floats = 528384 float4
    zero_kernel<<<dim3(2064), 256, 0, stream>>>((float4*)d_ws);
    pack_pf    <<<dim3(64, 2, NB),  256, 0, stream>>>(pf, pfC, pfT);
    fc2_kernel <<<dim3(64, 4, NB),  256, 0, stream>>>(img, fc2w, fc2b, riC, riT);
    stats_mfma <<<dim3(64, NB, 8),  256, 0, stream>>>(pfT, riT, zrsum, zcsum);
    attn_mfma  <<<dim3(64, NB, 8),  256, 0, stream>>>(pfT, riT, pfC, riC, zrsum, zcsum, fus);
    conv_kernel<<<dim3(64, 4, NB),  256, 0, stream>>>(fus, cw, cb, g, be, mu, var, out);
}

// Round 8
// 295.728 us; speedup vs baseline: 4.9984x; 1.0570x over previous
//
#include <hip/hip_runtime.h>
#include <math.h>

// Problem constants
#define NTOK 4096
#define PCH  128
#define ICH  256
#define OCH  128
#define NB   2
#define SCALEF 0.08838834764831845f   // 1/sqrt(128)

typedef __bf16 bf16_t;
typedef __attribute__((ext_vector_type(8))) __bf16 bf16x8;
typedef __attribute__((ext_vector_type(4))) __bf16 bf16x4;
typedef __attribute__((ext_vector_type(4))) float floatx4;

#define LDK 136   // padded row length (bf16 elems) for k=128 tiles
#define LDJ 72    // padded row length for j=64 tiles

// ---------------------------------------------------------------------------
// K-1: zero fus (8 MB) + zsum buffers (64 KB) — contiguous at ws start.
// ---------------------------------------------------------------------------
__global__ __launch_bounds__(256) void zero_kernel(float4* __restrict__ p)
{
    p[(size_t)blockIdx.x * 256 + threadIdx.x] = float4{0.f, 0.f, 0.f, 0.f};
}

// ---------------------------------------------------------------------------
// K0: pack pf -> pfC (bf16 channel-major) + pfT (bf16 token-major)
// ---------------------------------------------------------------------------
__global__ __launch_bounds__(256) void pack_pf(const float* __restrict__ pf,
                                               bf16_t* __restrict__ pfC,
                                               bf16_t* __restrict__ pfT)
{
    __shared__ float Ls[64][65];
    const int t = threadIdx.x;
    const int n0 = blockIdx.x * 64, d0 = blockIdx.y * 64, b = blockIdx.z;
    const float* src = pf + ((size_t)(b * PCH + d0)) * NTOK + n0;
#pragma unroll
    for (int p = 0; p < 4; p++) {
        int d = p * 16 + (t >> 4), c = t & 15;
        float4 v = *(const float4*)&src[d * NTOK + c * 4];
        Ls[d][c * 4 + 0] = v.x; Ls[d][c * 4 + 1] = v.y;
        Ls[d][c * 4 + 2] = v.z; Ls[d][c * 4 + 3] = v.w;
        bf16x4 o = { (bf16_t)v.x, (bf16_t)v.y, (bf16_t)v.z, (bf16_t)v.w };
        *(bf16x4*)&pfC[((size_t)(b * PCH + d0 + d)) * NTOK + n0 + c * 4] = o;
    }
    __syncthreads();
#pragma unroll
    for (int p = 0; p < 2; p++) {
        int n = p * 32 + (t >> 3), c = t & 7;
        bf16x8 o;
#pragma unroll
        for (int k = 0; k < 8; k++) o[k] = (bf16_t)Ls[c * 8 + k][n];
        *(bf16x8*)&pfT[((size_t)(b * NTOK + n0 + n)) * PCH + d0 + c * 8] = o;
    }
}

// ---------------------------------------------------------------------------
// K1: fc2 — ri[b][p][n] = sum_c img[b][c][n]*w[p][c] + bias[p]
// ---------------------------------------------------------------------------
__global__ __launch_bounds__(256) void fc2_kernel(const float* __restrict__ img,
                                                  const float* __restrict__ w,
                                                  const float* __restrict__ bias,
                                                  bf16_t* __restrict__ riC,
                                                  bf16_t* __restrict__ riT)
{
    const int b = blockIdx.z, t = threadIdx.x;
    const int n = blockIdx.x * 64 + (t & 63);
    const int pbase = blockIdx.y * 32 + (t >> 6) * 8;   // wave-uniform
    const float* imgb = img + (size_t)b * ICH * NTOK + n;

    float acc[8];
#pragma unroll
    for (int pp = 0; pp < 8; pp++) acc[pp] = bias[pbase + pp];

    for (int c = 0; c < ICH; c += 4) {
        float v0 = imgb[(c + 0) * NTOK];
        float v1 = imgb[(c + 1) * NTOK];
        float v2 = imgb[(c + 2) * NTOK];
        float v3 = imgb[(c + 3) * NTOK];
#pragma unroll
        for (int pp = 0; pp < 8; pp++) {
            float4 wv = *(const float4*)&w[(pbase + pp) * ICH + c];
            acc[pp] += wv.x * v0 + wv.y * v1 + wv.z * v2 + wv.w * v3;
        }
    }

#pragma unroll
    for (int pp = 0; pp < 8; pp++)
        riC[((size_t)(b * PCH + pbase + pp)) * NTOK + n] = (bf16_t)acc[pp];
    bf16x8 tv;
#pragma unroll
    for (int pp = 0; pp < 8; pp++) tv[pp] = (bf16_t)acc[pp];
    *(bf16x8*)&riT[((size_t)(b * NTOK + n)) * PCH + pbase] = tv;
}

// ---------------------------------------------------------------------------
// K2: stats v4 — ONE pass over E = exp(scale * pf_i . ri_j), BOTH reductions:
//   zr[i] += sum_j E[i,j]   (row sums;  mode1's normalizer)
//   zc[j] += sum_i E[i,j]   (col sums;  mode0's normalizer)
// s_i = S^T  =>  mode1 row sums == col sums of the SAME E. Halves stats work.
// Coalesced double-buffered LDS staging of B (R6 pattern), 1 barrier/tile.
// blockIdx.z = js (j quarter). Grid 64*NB*4 = 512.
// ---------------------------------------------------------------------------
__global__ __launch_bounds__(256, 3) void stats_mfma(const bf16_t* __restrict__ pfT,
                                                     const bf16_t* __restrict__ riT,
                                                     float* __restrict__ zr,
                                                     float* __restrict__ zc)
{
    __shared__ bf16_t As[64 * LDK];
    __shared__ bf16_t Bs[2][64 * LDK];
    const int b = blockIdx.y, t = threadIdx.x;
    const int js = blockIdx.z;
    const bf16_t* At = pfT + (size_t)b * NTOK * PCH;
    const bf16_t* Bt = riT + (size_t)b * NTOK * PCH;
    float* zrow = zr + (size_t)b * NTOK;
    float* zcol = zc + (size_t)b * NTOK;
    const int lane = t & 63, w = t >> 6, tx = lane & 15, q = lane >> 4;
    const int i0 = blockIdx.x * 64;
    const int jbase = js * 1024;
    const int sr = t >> 4, sc = t & 15;

    // first B tile into registers, then stage A band (all coalesced uint4)
    uint4 breg[4];
#pragma unroll
    for (int p = 0; p < 4; p++)
        breg[p] = *(const uint4*)&Bt[((size_t)(jbase + p * 16 + sr)) * PCH + sc * 8];
#pragma unroll
    for (int p = 0; p < 4; p++) {
        int i = p * 16 + sr;
        *(uint4*)&As[i * LDK + sc * 8] = *(const uint4*)&At[((size_t)(i0 + i)) * PCH + sc * 8];
    }
    __syncthreads();
    bf16x8 af[4][4];
#pragma unroll
    for (int mt = 0; mt < 4; mt++)
#pragma unroll
        for (int s = 0; s < 4; s++)
            af[mt][s] = *(bf16x8*)&As[(mt * 16 + tx) * LDK + s * 32 + q * 8];

    // stage Bs[0], prefetch tile 1
#pragma unroll
    for (int p = 0; p < 4; p++)
        *(uint4*)&Bs[0][(p * 16 + sr) * LDK + sc * 8] = breg[p];
#pragma unroll
    for (int p = 0; p < 4; p++)
        breg[p] = *(const uint4*)&Bt[((size_t)(jbase + 64 + p * 16 + sr)) * PCH + sc * 8];

    float racc[4] = {0.f, 0.f, 0.f, 0.f};
    for (int jt = 0; jt < 16; jt++) {
        const int cur = jt & 1;
        const int j0 = jbase + jt * 64;
        __syncthreads();                         // Bs[cur] visible; prev reads done
        bf16x8 bfr[4];
#pragma unroll
        for (int s = 0; s < 4; s++)
            bfr[s] = *(bf16x8*)&Bs[cur][(w * 16 + tx) * LDK + s * 32 + q * 8];
        if (jt < 15) {                           // stage next buf while cur is read
#pragma unroll
            for (int p = 0; p < 4; p++)
                *(uint4*)&Bs[cur ^ 1][(p * 16 + sr) * LDK + sc * 8] = breg[p];
            if (jt < 14) {
                const int j0n = jbase + (jt + 2) * 64;
#pragma unroll
                for (int p = 0; p < 4; p++)
                    breg[p] = *(const uint4*)&Bt[((size_t)(j0n + p * 16 + sr)) * PCH + sc * 8];
            }
        }

        // swapped GEMM: lane holds E^T tile: j = j0+w*16+q*4+r, i = i0+mt*16+tx
        floatx4 sacc[4];
#pragma unroll
        for (int mt = 0; mt < 4; mt++) {
            sacc[mt] = (floatx4){0.f, 0.f, 0.f, 0.f};
#pragma unroll
            for (int s = 0; s < 4; s++)
                sacc[mt] = __builtin_amdgcn_mfma_f32_16x16x32_bf16(bfr[s], af[mt][s], sacc[mt], 0, 0, 0);
        }

        float e[4][4];
        float ctmp[4] = {0.f, 0.f, 0.f, 0.f};
#pragma unroll
        for (int mt = 0; mt < 4; mt++)
#pragma unroll
            for (int r = 0; r < 4; r++) {
                e[mt][r] = __expf(sacc[mt][r] * SCALEF);
                racc[mt] += e[mt][r];            // row partial (over j)
                ctmp[r]  += e[mt][r];            // col partial (over i in-lane)
            }
        // col sums: reduce over the 16 tx lanes, flush per tile (j changes per jt)
#pragma unroll
        for (int r = 0; r < 4; r++) {
            float v = ctmp[r];
            v += __shfl_xor(v, 1); v += __shfl_xor(v, 2);
            v += __shfl_xor(v, 4); v += __shfl_xor(v, 8);
            if (tx == 0) atomicAdd(&zcol[j0 + w * 16 + q * 4 + r], v);
        }
    }
    // row sums: combine quads (xor 16, 32) then one atomic per i per wave
#pragma unroll
    for (int mt = 0; mt < 4; mt++) {
        float v = racc[mt];
        v += __shfl_xor(v, 16);
        v += __shfl_xor(v, 32);
        if (q == 0) atomicAdd(&zrow[i0 + mt * 16 + tx], v);
    }
}

// ---------------------------------------------------------------------------
// K3: attn — fus[i][d] += sum_{j in quarter} exp(scale*A_i.B_j)/zsum[j]*A_j[d]
// (unchanged from R7: direct global B/V-frag prefetch, swapped GEMM1, Es dbuf,
//  one barrier per j-tile)
// ---------------------------------------------------------------------------
__global__ __launch_bounds__(256, 3) void attn_mfma(const bf16_t* __restrict__ pfT,
                                                    const bf16_t* __restrict__ riT,
                                                    const bf16_t* __restrict__ pfC,
                                                    const bf16_t* __restrict__ riC,
                                                    const float* __restrict__ zrsum,
                                                    const float* __restrict__ zcsum,
                                                    float* __restrict__ fus)
{
    __shared__ bf16_t As[64 * LDK];
    __shared__ bf16_t Es[2][64 * LDJ];
    const int b = blockIdx.y, t = threadIdx.x;
    const int mode = blockIdx.z >> 2, js = blockIdx.z & 3;
    const bf16_t* At = (mode == 0 ? pfT : riT) + (size_t)b * NTOK * PCH;
    const bf16_t* Bt = (mode == 0 ? riT : pfT) + (size_t)b * NTOK * PCH;
    const bf16_t* Vc = (mode == 0 ? pfC : riC) + (size_t)b * PCH * NTOK;
    const float* wsum = (mode == 0 ? zcsum : zrsum) + (size_t)b * NTOK;
    const int lane = t & 63, w = t >> 6, tx = lane & 15, q = lane >> 4;
    const int i0 = blockIdx.x * 64;
    const int jbase = js * 1024;
    const int sr = t >> 4, sc = t & 15;
    const bf16_t* Brow = Bt + (size_t)(jbase + w * 16 + tx) * PCH;

    bf16x8 bcur[4];
#pragma unroll
    for (int s = 0; s < 4; s++)
        bcur[s] = *(const bf16x8*)&Brow[s * 32 + q * 8];
    bf16x8 vcur[2][2];
#pragma unroll
    for (int nt = 0; nt < 2; nt++)
#pragma unroll
        for (int s = 0; s < 2; s++)
            vcur[nt][s] = *(const bf16x8*)&Vc[((size_t)(w * 32 + nt * 16 + tx)) * NTOK + jbase + s * 32 + q * 8];
    float4 wv = *(const float4*)&wsum[jbase + w * 16 + q * 4];
    float4 wr4 = {1.f / wv.x, 1.f / wv.y, 1.f / wv.z, 1.f / wv.w};

#pragma unroll
    for (int p = 0; p < 4; p++) {
        int i = p * 16 + sr;
        *(uint4*)&As[i * LDK + sc * 8] = *(const uint4*)&At[((size_t)(i0 + i)) * PCH + sc * 8];
    }
    __syncthreads();
    bf16x8 af[4][4];
#pragma unroll
    for (int mt = 0; mt < 4; mt++)
#pragma unroll
        for (int s = 0; s < 4; s++)
            af[mt][s] = *(bf16x8*)&As[(mt * 16 + tx) * LDK + s * 32 + q * 8];

    floatx4 outacc[4][2];
#pragma unroll
    for (int mt = 0; mt < 4; mt++)
#pragma unroll
        for (int nt = 0; nt < 2; nt++)
            outacc[mt][nt] = (floatx4){0.f, 0.f, 0.f, 0.f};

    for (int jt = 0; jt < 16; jt++) {
        const int cur = jt & 1;
        const int j0 = jbase + jt * 64;

        floatx4 sacc[4];
#pragma unroll
        for (int mt = 0; mt < 4; mt++) {
            sacc[mt] = (floatx4){0.f, 0.f, 0.f, 0.f};
#pragma unroll
            for (int s = 0; s < 4; s++)
                sacc[mt] = __builtin_amdgcn_mfma_f32_16x16x32_bf16(bcur[s], af[mt][s], sacc[mt], 0, 0, 0);
        }
        if (jt < 15) {
            const bf16_t* bn = Brow + (size_t)(jt + 1) * 64 * PCH;
#pragma unroll
            for (int s = 0; s < 4; s++)
                bcur[s] = *(const bf16x8*)&bn[s * 32 + q * 8];
        }

#pragma unroll
        for (int mt = 0; mt < 4; mt++) {
            bf16x4 ev;
#pragma unroll
            for (int r = 0; r < 4; r++)
                ev[r] = (bf16_t)(__expf(sacc[mt][r] * SCALEF) * ((const float*)&wr4)[r]);
            *(bf16x4*)&Es[cur][(mt * 16 + tx) * LDJ + w * 16 + q * 4] = ev;
        }
        float4 wnv;
        if (jt < 15)
            wnv = *(const float4*)&wsum[j0 + 64 + w * 16 + q * 4];

        __syncthreads();

        bf16x8 ef[4][2];
#pragma unroll
        for (int mt = 0; mt < 4; mt++)
#pragma unroll
            for (int s = 0; s < 2; s++)
                ef[mt][s] = *(bf16x8*)&Es[cur][(mt * 16 + tx) * LDJ + s * 32 + q * 8];
#pragma unroll
        for (int nt = 0; nt < 2; nt++)
#pragma unroll
            for (int s = 0; s < 2; s++)
#pragma unroll
                for (int mt = 0; mt < 4; mt++)
                    outacc[mt][nt] = __builtin_amdgcn_mfma_f32_16x16x32_bf16(ef[mt][s], vcur[nt][s], outacc[mt][nt], 0, 0, 0);

        if (jt < 15) {
#pragma unroll
            for (int nt = 0; nt < 2; nt++)
#pragma unroll
                for (int s = 0; s < 2; s++)
                    vcur[nt][s] = *(const bf16x8*)&Vc[((size_t)(w * 32 + nt * 16 + tx)) * NTOK + (j0 + 64) + s * 32 + q * 8];
            wr4 = (float4){1.f / wnv.x, 1.f / wnv.y, 1.f / wnv.z, 1.f / wnv.w};
        }
    }

    float* fo = fus + ((size_t)(b * NTOK + i0)) * 256 + mode * 128 + w * 32;
#pragma unroll
    for (int mt = 0; mt < 4; mt++)
#pragma unroll
        for (int nt = 0; nt < 2; nt++)
#pragma unroll
            for (int r = 0; r < 4; r++)
                atomicAdd(&fo[(mt * 16 + q * 4 + r) * 256 + nt * 16 + tx], outacc[mt][nt][r]);
}

// ---------------------------------------------------------------------------
// K4: 1x1 conv (256 -> 128) + BN(eval) + ReLU.
// ---------------------------------------------------------------------------
__global__ __launch_bounds__(256) void conv_kernel(const float* __restrict__ fus,
                                                   const float* __restrict__ cw,
                                                   const float* __restrict__ cb,
                                                   const float* __restrict__ g,
                                                   const float* __restrict__ be,
                                                   const float* __restrict__ mu,
                                                   const float* __restrict__ var,
                                                   float* __restrict__ out)
{
    __shared__ float Ls[64][260];
    const int b = blockIdx.z, t = threadIdx.x;
    const int n0 = blockIdx.x * 64;
    const int obase = blockIdx.y * 32 + (t >> 6) * 8;   // wave-uniform

    const float4* src = (const float4*)(fus + ((size_t)(b * NTOK + n0)) * 256);
#pragma unroll
    for (int it = 0; it < 16; it++) {
        int row = it * 4 + (t >> 6);
        float4 v = src[row * 64 + (t & 63)];
        *(float4*)&Ls[row][(t & 63) * 4] = v;
    }
    __syncthreads();

    const int n = t & 63;
    float acc[8] = {};
    for (int c = 0; c < 256; c += 4) {
        float4 v = *(const float4*)&Ls[n][c];
#pragma unroll
        for (int oo = 0; oo < 8; oo++) {
            float4 wv = *(const float4*)&cw[(obase + oo) * 256 + c];
            acc[oo] += wv.x * v.x + wv.y * v.y + wv.z * v.z + wv.w * v.w;
        }
    }
#pragma unroll
    for (int oo = 0; oo < 8; oo++) {
        const int o = obase + oo;
        const float s  = g[o] * rsqrtf(var[o] + 1e-5f);
        const float b0 = be[o] + (cb[o] - mu[o]) * s;
        float y = acc[oo] * s + b0;
        out[((size_t)(b * OCH + o)) * NTOK + n0 + n] = fmaxf(y, 0.f);
    }
}

// ---------------------------------------------------------------------------
extern "C" void kernel_launch(void* const* d_in, const int* in_sizes, int n_in,
                              void* d_out, int out_size, void* d_ws, size_t ws_size,
                              hipStream_t stream)
{
    const float* pf   = (const float*)d_in[0];
    const float* img  = (const float*)d_in[1];
    const float* fc2w = (const float*)d_in[2];
    const float* fc2b = (const float*)d_in[3];
    const float* cw   = (const float*)d_in[4];
    const float* cb   = (const float*)d_in[5];
    const float* g    = (const float*)d_in[6];
    const float* be   = (const float*)d_in[7];
    const float* mu   = (const float*)d_in[8];
    const float* var  = (const float*)d_in[9];
    float* out = (float*)d_out;

    // ws layout: EXACTLY the proven footprint (16,842,752 B).
    float* fus   = (float*)d_ws;                              // 8 MB
    float* zrsum = fus + (size_t)NB * NTOK * 256;             // 32 KB
    float* zcsum = zrsum + NB * NTOK;                         // 32 KB
    bf16_t* pfC = (bf16_t*)(zcsum + NB * NTOK);               // 2 MB
    bf16_t* pfT = pfC + (size_t)NB * PCH * NTOK;              // 2 MB
    bf16_t* riC = pfT + (size_t)NB * NTOK * PCH;              // 2 MB
    bf16_t* riT = riC + (size_t)NB * PCH * NTOK;              // 2 MB

    // zero fus + zsums: (2*4096*256 + 2*2*4096) floats = 528384 float4
    zero_kernel<<<dim3(2064), 256, 0, stream>>>((float4*)d_ws);
    pack_pf    <<<dim3(64, 2, NB),  256, 0, stream>>>(pf, pfC, pfT);
    fc2_kernel <<<dim3(64, 4, NB),  256, 0, stream>>>(img, fc2w, fc2b, riC, riT);
    stats_mfma <<<dim3(64, NB, 4),  256, 0, stream>>>(pfT, riT, zrsum, zcsum);
    attn_mfma  <<<dim3(64, NB, 8),  256, 0, stream>>>(pfT, riT, pfC, riC, zrsum, zcsum, fus);
    conv_kernel<<<dim3(64, 4, NB),  256, 0, stream>>>(fus, cw, cb, g, be, mu, var, out);
}